// Round 4
// baseline (1362.553 us; speedup 1.0000x reference)
//
#include <hip/hip_runtime.h>
#include <hip/hip_bf16.h>

#define FD 128

__device__ __forceinline__ float bfu2f(unsigned short u) {
  return __uint_as_float(((unsigned int)u) << 16);
}
__device__ __forceinline__ float b2f(__hip_bfloat16 v) { return __bfloat162float(v); }

// flag-dispatched external loads: ff=1 -> fp32, ff=0 -> bf16 ; fi=1 -> int64
__device__ __forceinline__ float ldf(const void* p, int i, int ff) {
  return ff ? ((const float*)p)[i] : b2f(((const __hip_bfloat16*)p)[i]);
}
__device__ __forceinline__ int ldi(const void* p, int i, int fi) {
  return fi ? (int)((const long long*)p)[i] : ((const int*)p)[i];
}

// ---------------- dtype detection ----------------
__global__ void detect_k(const void* x, const void* cols, int* flags) {
  __shared__ int cnt[2];
  if (threadIdx.x < 2) cnt[threadIdx.x] = 0;
  __syncthreads();
  const unsigned short* xu = (const unsigned short*)x;
  int big = 0;
  for (int i = threadIdx.x; i < 1024; i += 256) {
    int e = (xu[i] >> 7) & 0xFF;       // bf16 exponent field
    if (e >= 0x90) big++;              // |v| >= 2^17: impossible for N(0,1) bf16
  }
  if (big) atomicAdd(&cnt[0], big);
  const int* ci = (const int*)cols;
  int zeros = 0;
  for (int i = threadIdx.x; i < 128; i += 256)
    if ((i & 1) && ci[i] == 0) zeros++; // int64 high words are all zero
  if (zeros) atomicAdd(&cnt[1], zeros);
  __syncthreads();
  if (threadIdx.x == 0) {
    flags[0] = (cnt[0] > 16) ? 1 : 0;
    flags[1] = (cnt[1] >= 32) ? 1 : 0;
  }
}

// ---------------- setup kernels ----------------

__global__ void hist_k(const void* __restrict__ r, const void* __restrict__ c,
                       const void* __restrict__ v, int nnz,
                       float* u1, float* v1, int* cntT, const int* flags) {
  int ff = flags[0], fi = flags[1];
  int i = blockIdx.x * 256 + threadIdx.x;
  if (i >= nnz) return;
  float vv = ldf(v, i, ff);
  int ri = ldi(r, i, fi), ci = ldi(c, i, fi);
  if ((unsigned)ri >= 50000u) ri = 0;
  if ((unsigned)ci >= 50000u) ci = 0;
  atomicAdd(&u1[ri], vv);
  atomicAdd(&v1[ci], vv);
  atomicAdd(&cntT[ci], 1);
}

__global__ void scan_k(const int* __restrict__ cnt, int n, int* rp, int* cur) {
  __shared__ int sh[1024];
  int t = threadIdx.x;
  int chunk = (n + 1023) >> 10;
  int s = t * chunk, e = min(s + chunk, n);
  int sum = 0;
  for (int i = s; i < e; ++i) sum += cnt[i];
  sh[t] = sum;
  __syncthreads();
  int val = sum;
  for (int d = 1; d < 1024; d <<= 1) {
    int add = (t >= d) ? sh[t - d] : 0;
    __syncthreads();
    val += add;
    sh[t] = val;
    __syncthreads();
  }
  int off = val - sum;
  for (int i = s; i < e; ++i) {
    rp[i] = off; cur[i] = off; off += cnt[i];
  }
  if (t == 1023) rp[n] = sh[1023];
}

__global__ void bsearch_k(const void* __restrict__ rows, int nnz, int n, int* rpA,
                          const int* flags) {
  int fi = flags[1];
  int i = blockIdx.x * 256 + threadIdx.x;
  if (i > n) return;
  int lo = 0, hi = nnz;
  while (lo < hi) { int mid = (lo + hi) >> 1; if (ldi(rows, mid, fi) < i) lo = mid + 1; else hi = mid; }
  rpA[i] = lo;
}

__global__ void scatter_k(const void* __restrict__ r, const void* __restrict__ c,
                          const void* __restrict__ v, int nnz,
                          int* cur, int* tSrc, float* tVal, const int* flags) {
  int ff = flags[0], fi = flags[1];
  int i = blockIdx.x * 256 + threadIdx.x;
  if (i >= nnz) return;
  int cc = ldi(c, i, fi);
  if ((unsigned)cc >= 50000u) cc = 0;
  int p = atomicAdd(&cur[cc], 1);
  if ((unsigned)p >= (unsigned)nnz) return;
  int rr = ldi(r, i, fi);
  if ((unsigned)rr >= 50000u) rr = 0;
  tSrc[p] = rr;
  tVal[p] = ldf(v, i, ff);
}

__global__ void deg2_k(const void* __restrict__ r, const void* __restrict__ c,
                       const void* __restrict__ v, int nnz,
                       const float* __restrict__ u1, const float* __restrict__ v1,
                       float* e1, float* e2, float* e3, float* e4, const int* flags) {
  int ff = flags[0], fi = flags[1];
  int i = blockIdx.x * 256 + threadIdx.x;
  if (i >= nnz) return;
  int ri = ldi(r, i, fi), ci = ldi(c, i, fi);
  if ((unsigned)ri >= 50000u) ri = 0;
  if ((unsigned)ci >= 50000u) ci = 0;
  float vv = ldf(v, i, ff);
  atomicAdd(&e1[ri], vv * v1[ci]);
  atomicAdd(&e3[ri], vv * u1[ci]);
  atomicAdd(&e2[ci], vv * u1[ri]);
  atomicAdd(&e4[ci], vv * v1[ri]);
}

__global__ void rsqrt_k(const float* __restrict__ e, float* __restrict__ s, int n) {
  int i = blockIdx.x * 256 + threadIdx.x;
  if (i >= n) return;
  float x = e[i];
  s[i] = (x > 0.f) ? rsqrtf(x) : 0.f;
}

__global__ void bias_k(const void* a, const void* b, const void* c, const void* d,
                       const void* e, const void* f, float* bias, const int* flags) {
  int ff = flags[0];
  int i = threadIdx.x;
  bias[i] = 0.5f * (ldf(a, i, ff) + ldf(b, i, ff) + ldf(c, i, ff)
                  + ldf(d, i, ff) + ldf(e, i, ff) + ldf(f, i, ff));
}

__global__ void fill_k(unsigned short* o, int n) {
  int i = blockIdx.x * 256 + threadIdx.x;
  if (i < n) o[i] = 0x3E80;
}

// ---------------- CSR spmm ----------------
// y(bf16)[r,t] = rscale[r] * sum_j val(j)*cscale[c]*xval(c,t)
// ci width: cif=1 -> follows int flag, 0 -> int32 internal.
// cv: cvf=1 -> fp32 internal, 0 -> follows float flag.
// x:  xf=1 -> external (float flag), 0 -> bf16 internal.
__global__ __launch_bounds__(128) void spmm_k(
    const int* __restrict__ rp, const void* __restrict__ ci, int cif,
    const void* __restrict__ cv, int cvf,
    const void* __restrict__ x, int xf, __hip_bfloat16* __restrict__ y,
    int n, int nnzMax,
    const float* __restrict__ cscale, const float* __restrict__ rscale,
    const int* flags) {
  int ff = flags[0], fi = flags[1];
  int vf = cvf ? 1 : ff;
  int iw = cif ? fi : 0;
  int xw = xf ? ff : 0;  // 0 = bf16, 1 = fp32
  const int t = threadIdx.x;
  int r0 = blockIdx.x * 4;
  int rend = min(r0 + 4, n);
  for (int r = r0; r < rend; ++r) {
    int s = rp[r], e = rp[r + 1];
    s = max(0, min(s, nnzMax));
    e = max(s, min(e, nnzMax));
    float acc = 0.f;
    for (int j = s; j < e; ++j) {
      int c = ldi(ci, j, iw);
      if ((unsigned)c >= (unsigned)n) c = 0;
      float v = (vf ? ((const float*)cv)[j] : b2f(((const __hip_bfloat16*)cv)[j]));
      if (cscale) v *= cscale[c];
      float xv = xw ? ((const float*)x)[c * FD + t]
                    : b2f(((const __hip_bfloat16*)x)[c * FD + t]);
      acc = fmaf(v, xv, acc);
    }
    if (rscale) acc *= rscale[r];
    y[r * FD + t] = __float2bfloat16(acc);
  }
}

// ---------------- GEMM ----------------
__global__ __launch_bounds__(256) void gemm_k(
    const __hip_bfloat16* __restrict__ Y, const void* __restrict__ W,
    const float* __restrict__ bias, const void* __restrict__ accin,
    void* __restrict__ outp, int M, const int* flags) {
  int ff = flags[0];
  __shared__ __align__(16) float Wl[32 * 128];
  __shared__ __align__(16) float Yl[64 * 36];
  const int t = threadIdx.x;
  const int row0 = blockIdx.x * 64;
  const int c4 = (t & 31) * 4;
  const int r8 = (t >> 5) * 8;
  const int rs = t >> 3;
  const int q = t & 7;
  float acc[8][4];
#pragma unroll
  for (int m = 0; m < 8; ++m)
#pragma unroll
    for (int j = 0; j < 4; ++j) acc[m][j] = 0.f;

  for (int kc = 0; kc < 4; ++kc) {
    if (ff) {
      const float4* Wg4 = (const float4*)((const float*)W + kc * 32 * 128);
#pragma unroll
      for (int i = 0; i < 4; ++i)
        *(float4*)(Wl + (t + i * 256) * 4) = Wg4[t + i * 256];
    } else {
      const ushort4* Wg4 = (const ushort4*)((const unsigned short*)W + kc * 32 * 128);
#pragma unroll
      for (int i = 0; i < 4; ++i) {
        ushort4 u = Wg4[t + i * 256];
        int base = (t + i * 256) * 4;
        Wl[base + 0] = bfu2f(u.x);
        Wl[base + 1] = bfu2f(u.y);
        Wl[base + 2] = bfu2f(u.z);
        Wl[base + 3] = bfu2f(u.w);
      }
    }
#pragma unroll
    for (int i = 0; i < 2; ++i) {
      int rr = rs + i * 32;
      int grow = row0 + rr;
      ushort4 u = make_ushort4(0, 0, 0, 0);
      if (grow < M)
        u = *(const ushort4*)((const unsigned short*)Y + grow * FD + kc * 32 + q * 4);
      float* yd = Yl + rr * 36 + q * 4;
      yd[0] = bfu2f(u.x); yd[1] = bfu2f(u.y); yd[2] = bfu2f(u.z); yd[3] = bfu2f(u.w);
    }
    __syncthreads();
#pragma unroll
    for (int kk = 0; kk < 32; kk += 4) {
      float4 w0 = *(const float4*)(Wl + (kk + 0) * 128 + c4);
      float4 w1 = *(const float4*)(Wl + (kk + 1) * 128 + c4);
      float4 w2 = *(const float4*)(Wl + (kk + 2) * 128 + c4);
      float4 w3 = *(const float4*)(Wl + (kk + 3) * 128 + c4);
#pragma unroll
      for (int m = 0; m < 8; ++m) {
        float4 yv = *(const float4*)(Yl + (r8 + m) * 36 + kk);
        acc[m][0] = fmaf(yv.x, w0.x, acc[m][0]);
        acc[m][1] = fmaf(yv.x, w0.y, acc[m][1]);
        acc[m][2] = fmaf(yv.x, w0.z, acc[m][2]);
        acc[m][3] = fmaf(yv.x, w0.w, acc[m][3]);
        acc[m][0] = fmaf(yv.y, w1.x, acc[m][0]);
        acc[m][1] = fmaf(yv.y, w1.y, acc[m][1]);
        acc[m][2] = fmaf(yv.y, w1.z, acc[m][2]);
        acc[m][3] = fmaf(yv.y, w1.w, acc[m][3]);
        acc[m][0] = fmaf(yv.z, w2.x, acc[m][0]);
        acc[m][1] = fmaf(yv.z, w2.y, acc[m][1]);
        acc[m][2] = fmaf(yv.z, w2.z, acc[m][2]);
        acc[m][3] = fmaf(yv.z, w2.w, acc[m][3]);
        acc[m][0] = fmaf(yv.w, w3.x, acc[m][0]);
        acc[m][1] = fmaf(yv.w, w3.y, acc[m][1]);
        acc[m][2] = fmaf(yv.w, w3.z, acc[m][2]);
        acc[m][3] = fmaf(yv.w, w3.w, acc[m][3]);
      }
    }
    __syncthreads();
  }

  float4 b4 = make_float4(0.f, 0.f, 0.f, 0.f);
  if (bias) b4 = *(const float4*)(bias + c4);
#pragma unroll
  for (int m = 0; m < 8; ++m) {
    int grow = row0 + r8 + m;
    if (grow >= M) continue;
    float4 rv;
    rv.x = 0.5f * acc[m][0] + b4.x;
    rv.y = 0.5f * acc[m][1] + b4.y;
    rv.z = 0.5f * acc[m][2] + b4.z;
    rv.w = 0.5f * acc[m][3] + b4.w;
    if (accin) {
      if (ff) {
        float4 o = *(const float4*)((const float*)accin + grow * FD + c4);
        rv.x += o.x; rv.y += o.y; rv.z += o.z; rv.w += o.w;
      } else {
        ushort4 o = *(const ushort4*)((const unsigned short*)accin + grow * FD + c4);
        rv.x += bfu2f(o.x); rv.y += bfu2f(o.y); rv.z += bfu2f(o.z); rv.w += bfu2f(o.w);
      }
    }
    if (ff) {
      *(float4*)((float*)outp + grow * FD + c4) = rv;
    } else {
      ushort4 so;
      so.x = __bfloat16_as_ushort(__float2bfloat16(rv.x));
      so.y = __bfloat16_as_ushort(__float2bfloat16(rv.y));
      so.z = __bfloat16_as_ushort(__float2bfloat16(rv.z));
      so.w = __bfloat16_as_ushort(__float2bfloat16(rv.w));
      *(ushort4*)((unsigned short*)outp + grow * FD + c4) = so;
    }
  }
}

extern "C" void kernel_launch(void* const* d_in, const int* in_sizes, int n_in,
                              void* d_out, int out_size, void* d_ws, size_t ws_size,
                              hipStream_t stream) {
  const void* x    = d_in[0];
  const void* w_sd = d_in[1];
  const void* b_sd = d_in[2];
  const void* w_ds = d_in[3];
  const void* b_ds = d_in[4];
  const void* w0   = d_in[5];
  const void* b0   = d_in[6];
  const void* w1   = d_in[7];
  const void* b1   = d_in[8];
  const void* w2   = d_in[9];
  const void* b2   = d_in[10];
  const void* w3   = d_in[11];
  const void* b3   = d_in[12];
  const void* a_rows = d_in[13];
  const void* a_cols = d_in[14];
  const void* a_vals = d_in[15];
  const int nnz = in_sizes[13];
  const int N = in_sizes[0] / FD;

  size_t need = 0;
  auto lay = [&](size_t bytes) -> size_t {
    size_t off = need;
    need += (bytes + 255) & ~(size_t)255;
    return off;
  };
  size_t oYb   = lay((size_t)N * FD * 2);
  size_t oGb   = lay((size_t)N * FD * 2);
  size_t oDeg  = lay((size_t)10 * N * 4);
  size_t oBias = lay(FD * 4);
  size_t oFlag = lay(256);
  size_t oRpA  = lay((size_t)(N + 1) * 4);
  size_t oRpT  = lay((size_t)(N + 1) * 4);
  size_t oCur  = lay((size_t)N * 4);
  size_t oCnt  = lay((size_t)N * 4);
  size_t oTS   = lay((size_t)nnz * 4);
  size_t oTV   = lay((size_t)nnz * 4);

  if (ws_size < need) {
    fill_k<<<(out_size + 255) / 256, 256, 0, stream>>>((unsigned short*)d_out, out_size);
    return;
  }

  char* p = (char*)d_ws;
  __hip_bfloat16* Yb = (__hip_bfloat16*)(p + oYb);
  __hip_bfloat16* gb = (__hip_bfloat16*)(p + oGb);
  float* degf  = (float*)(p + oDeg);
  float* biasf = (float*)(p + oBias);
  int*   flags = (int*)(p + oFlag);
  int* rpA  = (int*)(p + oRpA);
  int* rpT  = (int*)(p + oRpT);
  int* curT = (int*)(p + oCur);
  int* cntT = (int*)(p + oCnt);
  int* tSrc = (int*)(p + oTS);
  float* tVal = (float*)(p + oTV);

  float* u1 = degf;
  float* v1 = degf + N;
  float* e1 = degf + 2 * N;
  float* s1 = degf + 6 * N;
  float* s2 = degf + 7 * N;
  float* s3 = degf + 8 * N;
  float* s4 = degf + 9 * N;

  int eb = (nnz + 255) / 256;

  detect_k<<<1, 256, 0, stream>>>(x, a_cols, flags);
  hipMemsetAsync(degf, 0, (size_t)6 * N * 4, stream);
  hipMemsetAsync(cntT, 0, (size_t)N * 4, stream);
  hist_k<<<eb, 256, 0, stream>>>(a_rows, a_cols, a_vals, nnz, u1, v1, cntT, flags);
  scan_k<<<1, 1024, 0, stream>>>(cntT, N, rpT, curT);
  bsearch_k<<<(N + 256) / 256, 256, 0, stream>>>(a_rows, nnz, N, rpA, flags);
  scatter_k<<<eb, 256, 0, stream>>>(a_rows, a_cols, a_vals, nnz, curT, tSrc, tVal, flags);
  deg2_k<<<eb, 256, 0, stream>>>(a_rows, a_cols, a_vals, nnz, u1, v1,
                                 e1, degf + 3 * N, degf + 4 * N, degf + 5 * N, flags);
  rsqrt_k<<<(4 * N + 255) / 256, 256, 0, stream>>>(e1, s1, 4 * N);
  bias_k<<<1, FD, 0, stream>>>(b_sd, b_ds, b0, b1, b2, b3, biasf, flags);

  int sg = (N + 3) / 4;
  int gg = (N + 63) / 64;

  // term 1: A x @ w_sd (adds summed bias; no accin)
  spmm_k<<<sg, 128, 0, stream>>>(rpA, a_cols, 1, a_vals, 0, x, 1, Yb, N, nnz, nullptr, nullptr, flags);
  gemm_k<<<gg, 256, 0, stream>>>(Yb, w_sd, biasf, nullptr, d_out, N, flags);
  // term 2: T x @ w_ds
  spmm_k<<<sg, 128, 0, stream>>>(rpT, tSrc, 0, tVal, 1, x, 1, Yb, N, nnz, nullptr, nullptr, flags);
  gemm_k<<<gg, 256, 0, stream>>>(Yb, w_ds, nullptr, d_out, d_out, N, flags);
  // term 3: aat = s1 . A(T(s1 . x)) @ w0
  spmm_k<<<sg, 128, 0, stream>>>(rpT, tSrc, 0, tVal, 1, x, 1, gb, N, nnz, s1, nullptr, flags);
  spmm_k<<<sg, 128, 0, stream>>>(rpA, a_cols, 1, a_vals, 0, gb, 0, Yb, N, nnz, nullptr, s1, flags);
  gemm_k<<<gg, 256, 0, stream>>>(Yb, w0, nullptr, d_out, d_out, N, flags);
  // term 4: ata = s2 . T(A(s2 . x)) @ w1
  spmm_k<<<sg, 128, 0, stream>>>(rpA, a_cols, 1, a_vals, 0, x, 1, gb, N, nnz, s2, nullptr, flags);
  spmm_k<<<sg, 128, 0, stream>>>(rpT, tSrc, 0, tVal, 1, gb, 0, Yb, N, nnz, nullptr, s2, flags);
  gemm_k<<<gg, 256, 0, stream>>>(Yb, w1, nullptr, d_out, d_out, N, flags);
  // term 5: aa = s3 . A(A(s4 . x)) @ w2
  spmm_k<<<sg, 128, 0, stream>>>(rpA, a_cols, 1, a_vals, 0, x, 1, gb, N, nnz, s4, nullptr, flags);
  spmm_k<<<sg, 128, 0, stream>>>(rpA, a_cols, 1, a_vals, 0, gb, 0, Yb, N, nnz, nullptr, s3, flags);
  gemm_k<<<gg, 256, 0, stream>>>(Yb, w2, nullptr, d_out, d_out, N, flags);
  // term 6: atat = s4 . T(T(s3 . x)) @ w3
  spmm_k<<<sg, 128, 0, stream>>>(rpT, tSrc, 0, tVal, 1, x, 1, gb, N, nnz, s3, nullptr, flags);
  spmm_k<<<sg, 128, 0, stream>>>(rpT, tSrc, 0, tVal, 1, gb, 0, Yb, N, nnz, nullptr, s4, flags);
  gemm_k<<<gg, 256, 0, stream>>>(Yb, w3, nullptr, d_out, d_out, N, flags);
}

// Round 5
// 863.579 us; speedup vs baseline: 1.5778x; 1.5778x over previous
//
#include <hip/hip_runtime.h>
#include <hip/hip_bf16.h>

#define FD 128

__device__ __forceinline__ float bfu2f(unsigned short u) {
  return __uint_as_float(((unsigned int)u) << 16);
}
__device__ __forceinline__ float b2f(__hip_bfloat16 v) { return __bfloat162float(v); }

// flag-dispatched external loads: ff=1 -> fp32, ff=0 -> bf16 ; fi=1 -> int64
__device__ __forceinline__ float ldf(const void* p, int i, int ff) {
  return ff ? ((const float*)p)[i] : b2f(((const __hip_bfloat16*)p)[i]);
}
__device__ __forceinline__ int ldi(const void* p, int i, int fi) {
  return fi ? (int)((const long long*)p)[i] : ((const int*)p)[i];
}

// ---------------- dtype detection ----------------
__global__ void detect_k(const void* x, const void* cols, int* flags) {
  __shared__ int cnt[2];
  if (threadIdx.x < 2) cnt[threadIdx.x] = 0;
  __syncthreads();
  const unsigned short* xu = (const unsigned short*)x;
  int big = 0;
  for (int i = threadIdx.x; i < 1024; i += 256) {
    int e = (xu[i] >> 7) & 0xFF;
    if (e >= 0x90) big++;
  }
  if (big) atomicAdd(&cnt[0], big);
  const int* ci = (const int*)cols;
  int zeros = 0;
  for (int i = threadIdx.x; i < 128; i += 256)
    if ((i & 1) && ci[i] == 0) zeros++;
  if (zeros) atomicAdd(&cnt[1], zeros);
  __syncthreads();
  if (threadIdx.x == 0) {
    flags[0] = (cnt[0] > 16) ? 1 : 0;
    flags[1] = (cnt[1] >= 32) ? 1 : 0;
  }
}

// ---------------- setup kernels ----------------

__global__ void hist_k(const void* __restrict__ r, const void* __restrict__ c,
                       const void* __restrict__ v, int nnz,
                       float* u1, float* v1, int* cntT, const int* flags) {
  int ff = flags[0], fi = flags[1];
  int i = blockIdx.x * 256 + threadIdx.x;
  if (i >= nnz) return;
  float vv = ldf(v, i, ff);
  int ri = ldi(r, i, fi), ci = ldi(c, i, fi);
  if ((unsigned)ri >= 50000u) ri = 0;
  if ((unsigned)ci >= 50000u) ci = 0;
  atomicAdd(&u1[ri], vv);
  atomicAdd(&v1[ci], vv);
  atomicAdd(&cntT[ci], 1);
}

// ---- parallel 3-pass scan ----
__global__ void scanA_k(const int* __restrict__ cnt, int n, int* bsum) {
  __shared__ int sh[256];
  int t = threadIdx.x;
  int i = blockIdx.x * 256 + t;
  sh[t] = (i < n) ? cnt[i] : 0;
  __syncthreads();
  for (int d = 128; d > 0; d >>= 1) {
    if (t < d) sh[t] += sh[t + d];
    __syncthreads();
  }
  if (t == 0) bsum[blockIdx.x] = sh[0];
}

__global__ void scanB_k(int* bsum, int nb, int* rpTail) {
  __shared__ int sh[256];
  int t = threadIdx.x;
  int v = (t < nb) ? bsum[t] : 0;
  sh[t] = v;
  __syncthreads();
  int val = v;
  for (int d = 1; d < 256; d <<= 1) {
    int add = (t >= d) ? sh[t - d] : 0;
    __syncthreads();
    val += add;
    sh[t] = val;
    __syncthreads();
  }
  if (t < nb) bsum[t] = val - v;     // exclusive block offsets
  if (t == 255) *rpTail = val;       // grand total -> rp[n]
}

__global__ void scanC_k(const int* __restrict__ cnt, int n, const int* __restrict__ bsum,
                        int* rp, int* cur) {
  __shared__ int sh[256];
  int t = threadIdx.x;
  int i = blockIdx.x * 256 + t;
  int v = (i < n) ? cnt[i] : 0;
  sh[t] = v;
  __syncthreads();
  int val = v;
  for (int d = 1; d < 256; d <<= 1) {
    int add = (t >= d) ? sh[t - d] : 0;
    __syncthreads();
    val += add;
    sh[t] = val;
    __syncthreads();
  }
  int ex = val - v + bsum[blockIdx.x];
  if (i < n) { rp[i] = ex; cur[i] = ex; }
}

__global__ void bsearch_k(const void* __restrict__ rows, int nnz, int n, int* rpA,
                          const int* flags) {
  int fi = flags[1];
  int i = blockIdx.x * 256 + threadIdx.x;
  if (i > n) return;
  int lo = 0, hi = nnz;
  while (lo < hi) { int mid = (lo + hi) >> 1; if (ldi(rows, mid, fi) < i) lo = mid + 1; else hi = mid; }
  rpA[i] = lo;
}

__global__ void scatter_k(const void* __restrict__ r, const void* __restrict__ c,
                          const void* __restrict__ v, int nnz,
                          int* cur, int* tSrc, float* tVal, const int* flags) {
  int ff = flags[0], fi = flags[1];
  int i = blockIdx.x * 256 + threadIdx.x;
  if (i >= nnz) return;
  int cc = ldi(c, i, fi);
  if ((unsigned)cc >= 50000u) cc = 0;
  int p = atomicAdd(&cur[cc], 1);
  if ((unsigned)p >= (unsigned)nnz) return;
  int rr = ldi(r, i, fi);
  if ((unsigned)rr >= 50000u) rr = 0;
  tSrc[p] = rr;
  tVal[p] = ldf(v, i, ff);
}

__global__ void deg2_k(const void* __restrict__ r, const void* __restrict__ c,
                       const void* __restrict__ v, int nnz,
                       const float* __restrict__ u1, const float* __restrict__ v1,
                       float* e1, float* e2, float* e3, float* e4, const int* flags) {
  int ff = flags[0], fi = flags[1];
  int i = blockIdx.x * 256 + threadIdx.x;
  if (i >= nnz) return;
  int ri = ldi(r, i, fi), ci = ldi(c, i, fi);
  if ((unsigned)ri >= 50000u) ri = 0;
  if ((unsigned)ci >= 50000u) ci = 0;
  float vv = ldf(v, i, ff);
  atomicAdd(&e1[ri], vv * v1[ci]);
  atomicAdd(&e3[ri], vv * u1[ci]);
  atomicAdd(&e2[ci], vv * u1[ri]);
  atomicAdd(&e4[ci], vv * v1[ri]);
}

__global__ void rsqrt_k(const float* __restrict__ e, float* __restrict__ s, int n) {
  int i = blockIdx.x * 256 + threadIdx.x;
  if (i >= n) return;
  float x = e[i];
  s[i] = (x > 0.f) ? rsqrtf(x) : 0.f;
}

__global__ void bias_k(const void* a, const void* b, const void* c, const void* d,
                       const void* e, const void* f, float* bias, const int* flags) {
  int ff = flags[0];
  int i = threadIdx.x;
  bias[i] = 0.5f * (ldf(a, i, ff) + ldf(b, i, ff) + ldf(c, i, ff)
                  + ldf(d, i, ff) + ldf(e, i, ff) + ldf(f, i, ff));
}

__global__ void fill_k(unsigned short* o, int n) {
  int i = blockIdx.x * 256 + threadIdx.x;
  if (i < n) o[i] = 0x3E80;
}

// x -> internal bf16
__global__ void cvtx_k(const void* __restrict__ x, __hip_bfloat16* __restrict__ xb,
                       int n, const int* flags) {
  int ff = flags[0];
  int i = (blockIdx.x * 256 + threadIdx.x) * 4;
  if (i + 3 >= n) {
    for (int k = i; k < n; ++k) xb[k] = __float2bfloat16(ldf(x, k, ff));
    return;
  }
  xb[i + 0] = __float2bfloat16(ldf(x, i + 0, ff));
  xb[i + 1] = __float2bfloat16(ldf(x, i + 1, ff));
  xb[i + 2] = __float2bfloat16(ldf(x, i + 2, ff));
  xb[i + 3] = __float2bfloat16(ldf(x, i + 3, ff));
}

// a_cols/a_vals -> internal int32/f32
__global__ void cvtav_k(const void* __restrict__ cols, const void* __restrict__ vals,
                        int nnz, int* __restrict__ c32, float* __restrict__ vf,
                        const int* flags) {
  int ff = flags[0], fi = flags[1];
  int i = blockIdx.x * 256 + threadIdx.x;
  if (i >= nnz) return;
  int c = ldi(cols, i, fi);
  if ((unsigned)c >= 50000u) c = 0;
  c32[i] = c;
  vf[i] = ldf(vals, i, ff);
}

// ---------------- Path B spmm (flag-dispatched, proven) ----------------
__global__ __launch_bounds__(128) void spmm_k(
    const int* __restrict__ rp, const void* __restrict__ ci, int cif,
    const void* __restrict__ cv, int cvf,
    const void* __restrict__ x, int xf, __hip_bfloat16* __restrict__ y,
    int n, int nnzMax,
    const float* __restrict__ cscale, const float* __restrict__ rscale,
    const int* flags) {
  int ff = flags[0], fi = flags[1];
  int vf = cvf ? 1 : ff;
  int iw = cif ? fi : 0;
  int xw = xf ? ff : 0;
  const int t = threadIdx.x;
  int r0 = blockIdx.x * 4;
  int rend = min(r0 + 4, n);
  for (int r = r0; r < rend; ++r) {
    int s = rp[r], e = rp[r + 1];
    s = max(0, min(s, nnzMax));
    e = max(s, min(e, nnzMax));
    float acc = 0.f;
    for (int j = s; j < e; ++j) {
      int c = ldi(ci, j, iw);
      if ((unsigned)c >= (unsigned)n) c = 0;
      float v = (vf ? ((const float*)cv)[j] : b2f(((const __hip_bfloat16*)cv)[j]));
      if (cscale) v *= cscale[c];
      float xv = xw ? ((const float*)x)[c * FD + t]
                    : b2f(((const __hip_bfloat16*)x)[c * FD + t]);
      acc = fmaf(v, xv, acc);
    }
    if (rscale) acc *= rscale[r];
    y[r * FD + t] = __float2bfloat16(acc);
  }
}

// ---------------- Path A fused first hop: 3 outputs share gathers ----------------
// ot = M.xb ; oa = M.(sA.xb) ; ob = M.(sB.xb)
__global__ __launch_bounds__(128) void fh_k(
    const int* __restrict__ rp, const int* __restrict__ ci, const float* __restrict__ cv,
    const __hip_bfloat16* __restrict__ xb,
    __hip_bfloat16* __restrict__ ot, __hip_bfloat16* __restrict__ oa,
    __hip_bfloat16* __restrict__ ob,
    const float* __restrict__ sA, const float* __restrict__ sB, int n, int nnzMax) {
  const int t = threadIdx.x;
  int r0 = blockIdx.x * 4, rend = min(r0 + 4, n);
  for (int r = r0; r < rend; ++r) {
    int s = rp[r], e = rp[r + 1];
    s = max(0, min(s, nnzMax));
    e = max(s, min(e, nnzMax));
    float at = 0.f, aa = 0.f, ab = 0.f;
    for (int j = s; j < e; ++j) {
      int c = ci[j];
      if ((unsigned)c >= (unsigned)n) c = 0;
      float v = cv[j];
      float xv = b2f(xb[c * FD + t]);
      float vx = v * xv;
      at += vx;
      aa = fmaf(vx, sA[c], aa);
      ab = fmaf(vx, sB[c], ab);
    }
    ot[r * FD + t] = __float2bfloat16(at);
    oa[r * FD + t] = __float2bfloat16(aa);
    ob[r * FD + t] = __float2bfloat16(ab);
  }
}

// ---------------- Path A second hop ----------------
__global__ __launch_bounds__(128) void sh_k(
    const int* __restrict__ rp, const int* __restrict__ ci, const float* __restrict__ cv,
    const __hip_bfloat16* __restrict__ g, __hip_bfloat16* __restrict__ y,
    const float* __restrict__ rscale, int n, int nnzMax) {
  const int t = threadIdx.x;
  int r0 = blockIdx.x * 4, rend = min(r0 + 4, n);
  for (int r = r0; r < rend; ++r) {
    int s = rp[r], e = rp[r + 1];
    s = max(0, min(s, nnzMax));
    e = max(s, min(e, nnzMax));
    float acc = 0.f;
    for (int j = s; j < e; ++j) {
      int c = ci[j];
      if ((unsigned)c >= (unsigned)n) c = 0;
      acc = fmaf(cv[j], b2f(g[c * FD + t]), acc);
    }
    y[r * FD + t] = __float2bfloat16(acc * rscale[r]);
  }
}

// ---------------- Path B GEMM (per-term, RMW accin) ----------------
__global__ __launch_bounds__(256) void gemm_k(
    const __hip_bfloat16* __restrict__ Y, const void* __restrict__ W,
    const float* __restrict__ bias, const void* __restrict__ accin,
    void* __restrict__ outp, int M, const int* flags) {
  int ff = flags[0];
  __shared__ __align__(16) float Wl[32 * 128];
  __shared__ __align__(16) float Yl[64 * 36];
  const int t = threadIdx.x;
  const int row0 = blockIdx.x * 64;
  const int c4 = (t & 31) * 4;
  const int r8 = (t >> 5) * 8;
  const int rs = t >> 3;
  const int q = t & 7;
  float acc[8][4];
#pragma unroll
  for (int m = 0; m < 8; ++m)
#pragma unroll
    for (int j = 0; j < 4; ++j) acc[m][j] = 0.f;

  for (int kc = 0; kc < 4; ++kc) {
    if (ff) {
      const float4* Wg4 = (const float4*)((const float*)W + kc * 32 * 128);
#pragma unroll
      for (int i = 0; i < 4; ++i)
        *(float4*)(Wl + (t + i * 256) * 4) = Wg4[t + i * 256];
    } else {
      const ushort4* Wg4 = (const ushort4*)((const unsigned short*)W + kc * 32 * 128);
#pragma unroll
      for (int i = 0; i < 4; ++i) {
        ushort4 u = Wg4[t + i * 256];
        int base = (t + i * 256) * 4;
        Wl[base + 0] = bfu2f(u.x);
        Wl[base + 1] = bfu2f(u.y);
        Wl[base + 2] = bfu2f(u.z);
        Wl[base + 3] = bfu2f(u.w);
      }
    }
#pragma unroll
    for (int i = 0; i < 2; ++i) {
      int rr = rs + i * 32;
      int grow = row0 + rr;
      ushort4 u = make_ushort4(0, 0, 0, 0);
      if (grow < M)
        u = *(const ushort4*)((const unsigned short*)Y + grow * FD + kc * 32 + q * 4);
      float* yd = Yl + rr * 36 + q * 4;
      yd[0] = bfu2f(u.x); yd[1] = bfu2f(u.y); yd[2] = bfu2f(u.z); yd[3] = bfu2f(u.w);
    }
    __syncthreads();
#pragma unroll
    for (int kk = 0; kk < 32; kk += 4) {
      float4 w0 = *(const float4*)(Wl + (kk + 0) * 128 + c4);
      float4 w1 = *(const float4*)(Wl + (kk + 1) * 128 + c4);
      float4 w2 = *(const float4*)(Wl + (kk + 2) * 128 + c4);
      float4 w3 = *(const float4*)(Wl + (kk + 3) * 128 + c4);
#pragma unroll
      for (int m = 0; m < 8; ++m) {
        float4 yv = *(const float4*)(Yl + (r8 + m) * 36 + kk);
        acc[m][0] = fmaf(yv.x, w0.x, acc[m][0]);
        acc[m][1] = fmaf(yv.x, w0.y, acc[m][1]);
        acc[m][2] = fmaf(yv.x, w0.z, acc[m][2]);
        acc[m][3] = fmaf(yv.x, w0.w, acc[m][3]);
        acc[m][0] = fmaf(yv.y, w1.x, acc[m][0]);
        acc[m][1] = fmaf(yv.y, w1.y, acc[m][1]);
        acc[m][2] = fmaf(yv.y, w1.z, acc[m][2]);
        acc[m][3] = fmaf(yv.y, w1.w, acc[m][3]);
        acc[m][0] = fmaf(yv.z, w2.x, acc[m][0]);
        acc[m][1] = fmaf(yv.z, w2.y, acc[m][1]);
        acc[m][2] = fmaf(yv.z, w2.z, acc[m][2]);
        acc[m][3] = fmaf(yv.z, w2.w, acc[m][3]);
        acc[m][0] = fmaf(yv.w, w3.x, acc[m][0]);
        acc[m][1] = fmaf(yv.w, w3.y, acc[m][1]);
        acc[m][2] = fmaf(yv.w, w3.z, acc[m][2]);
        acc[m][3] = fmaf(yv.w, w3.w, acc[m][3]);
      }
    }
    __syncthreads();
  }

  float4 b4 = make_float4(0.f, 0.f, 0.f, 0.f);
  if (bias) b4 = *(const float4*)(bias + c4);
#pragma unroll
  for (int m = 0; m < 8; ++m) {
    int grow = row0 + r8 + m;
    if (grow >= M) continue;
    float4 rv;
    rv.x = 0.5f * acc[m][0] + b4.x;
    rv.y = 0.5f * acc[m][1] + b4.y;
    rv.z = 0.5f * acc[m][2] + b4.z;
    rv.w = 0.5f * acc[m][3] + b4.w;
    if (accin) {
      if (ff) {
        float4 o = *(const float4*)((const float*)accin + grow * FD + c4);
        rv.x += o.x; rv.y += o.y; rv.z += o.z; rv.w += o.w;
      } else {
        ushort4 o = *(const ushort4*)((const unsigned short*)accin + grow * FD + c4);
        rv.x += bfu2f(o.x); rv.y += bfu2f(o.y); rv.z += bfu2f(o.z); rv.w += bfu2f(o.w);
      }
    }
    if (ff) {
      *(float4*)((float*)outp + grow * FD + c4) = rv;
    } else {
      ushort4 so;
      so.x = __bfloat16_as_ushort(__float2bfloat16(rv.x));
      so.y = __bfloat16_as_ushort(__float2bfloat16(rv.y));
      so.z = __bfloat16_as_ushort(__float2bfloat16(rv.z));
      so.w = __bfloat16_as_ushort(__float2bfloat16(rv.w));
      *(ushort4*)((unsigned short*)outp + grow * FD + c4) = so;
    }
  }
}

// ---------------- Path A fused GEMM: out = 0.5*sum_i Yi@Wi + bias ----------------
struct G6 {
  const __hip_bfloat16* y[6];
  const void* w[6];
};

__global__ __launch_bounds__(256) void gemm6_k(G6 args, const float* __restrict__ bias,
                                               void* __restrict__ outp, int M,
                                               const int* flags) {
  int ff = flags[0];
  __shared__ __align__(16) float Wl[32 * 128];
  __shared__ __align__(16) float Yl[64 * 36];
  const int t = threadIdx.x;
  const int row0 = blockIdx.x * 64;
  const int c4 = (t & 31) * 4;
  const int r8 = (t >> 5) * 8;
  const int rs = t >> 3;
  const int q = t & 7;
  float acc[8][4];
#pragma unroll
  for (int m = 0; m < 8; ++m)
#pragma unroll
    for (int j = 0; j < 4; ++j) acc[m][j] = 0.f;

  for (int seg = 0; seg < 6; ++seg) {
    const void* W = args.w[seg];
    const __hip_bfloat16* Y = args.y[seg];
    for (int kc = 0; kc < 4; ++kc) {
      if (ff) {
        const float4* Wg4 = (const float4*)((const float*)W + kc * 32 * 128);
#pragma unroll
        for (int i = 0; i < 4; ++i)
          *(float4*)(Wl + (t + i * 256) * 4) = Wg4[t + i * 256];
      } else {
        const ushort4* Wg4 = (const ushort4*)((const unsigned short*)W + kc * 32 * 128);
#pragma unroll
        for (int i = 0; i < 4; ++i) {
          ushort4 u = Wg4[t + i * 256];
          int base = (t + i * 256) * 4;
          Wl[base + 0] = bfu2f(u.x);
          Wl[base + 1] = bfu2f(u.y);
          Wl[base + 2] = bfu2f(u.z);
          Wl[base + 3] = bfu2f(u.w);
        }
      }
#pragma unroll
      for (int i = 0; i < 2; ++i) {
        int rr = rs + i * 32;
        int grow = row0 + rr;
        ushort4 u = make_ushort4(0, 0, 0, 0);
        if (grow < M)
          u = *(const ushort4*)((const unsigned short*)Y + grow * FD + kc * 32 + q * 4);
        float* yd = Yl + rr * 36 + q * 4;
        yd[0] = bfu2f(u.x); yd[1] = bfu2f(u.y); yd[2] = bfu2f(u.z); yd[3] = bfu2f(u.w);
      }
      __syncthreads();
#pragma unroll
      for (int kk = 0; kk < 32; kk += 4) {
        float4 w0 = *(const float4*)(Wl + (kk + 0) * 128 + c4);
        float4 w1 = *(const float4*)(Wl + (kk + 1) * 128 + c4);
        float4 w2 = *(const float4*)(Wl + (kk + 2) * 128 + c4);
        float4 w3 = *(const float4*)(Wl + (kk + 3) * 128 + c4);
#pragma unroll
        for (int m = 0; m < 8; ++m) {
          float4 yv = *(const float4*)(Yl + (r8 + m) * 36 + kk);
          acc[m][0] = fmaf(yv.x, w0.x, acc[m][0]);
          acc[m][1] = fmaf(yv.x, w0.y, acc[m][1]);
          acc[m][2] = fmaf(yv.x, w0.z, acc[m][2]);
          acc[m][3] = fmaf(yv.x, w0.w, acc[m][3]);
          acc[m][0] = fmaf(yv.y, w1.x, acc[m][0]);
          acc[m][1] = fmaf(yv.y, w1.y, acc[m][1]);
          acc[m][2] = fmaf(yv.y, w1.z, acc[m][2]);
          acc[m][3] = fmaf(yv.y, w1.w, acc[m][3]);
          acc[m][0] = fmaf(yv.z, w2.x, acc[m][0]);
          acc[m][1] = fmaf(yv.z, w2.y, acc[m][1]);
          acc[m][2] = fmaf(yv.z, w2.z, acc[m][2]);
          acc[m][3] = fmaf(yv.z, w2.w, acc[m][3]);
          acc[m][0] = fmaf(yv.w, w3.x, acc[m][0]);
          acc[m][1] = fmaf(yv.w, w3.y, acc[m][1]);
          acc[m][2] = fmaf(yv.w, w3.z, acc[m][2]);
          acc[m][3] = fmaf(yv.w, w3.w, acc[m][3]);
        }
      }
      __syncthreads();
    }
  }

  float4 b4 = *(const float4*)(bias + c4);
#pragma unroll
  for (int m = 0; m < 8; ++m) {
    int grow = row0 + r8 + m;
    if (grow >= M) continue;
    float4 rv;
    rv.x = 0.5f * acc[m][0] + b4.x;
    rv.y = 0.5f * acc[m][1] + b4.y;
    rv.z = 0.5f * acc[m][2] + b4.z;
    rv.w = 0.5f * acc[m][3] + b4.w;
    if (ff) {
      *(float4*)((float*)outp + grow * FD + c4) = rv;
    } else {
      ushort4 so;
      so.x = __bfloat16_as_ushort(__float2bfloat16(rv.x));
      so.y = __bfloat16_as_ushort(__float2bfloat16(rv.y));
      so.z = __bfloat16_as_ushort(__float2bfloat16(rv.z));
      so.w = __bfloat16_as_ushort(__float2bfloat16(rv.w));
      *(ushort4*)((unsigned short*)outp + grow * FD + c4) = so;
    }
  }
}

extern "C" void kernel_launch(void* const* d_in, const int* in_sizes, int n_in,
                              void* d_out, int out_size, void* d_ws, size_t ws_size,
                              hipStream_t stream) {
  const void* x    = d_in[0];
  const void* w_sd = d_in[1];
  const void* b_sd = d_in[2];
  const void* w_ds = d_in[3];
  const void* b_ds = d_in[4];
  const void* w0   = d_in[5];
  const void* b0   = d_in[6];
  const void* w1   = d_in[7];
  const void* b1   = d_in[8];
  const void* w2   = d_in[9];
  const void* b2   = d_in[10];
  const void* w3   = d_in[11];
  const void* b3   = d_in[12];
  const void* a_rows = d_in[13];
  const void* a_cols = d_in[14];
  const void* a_vals = d_in[15];
  const int nnz = in_sizes[13];
  const int N = in_sizes[0] / FD;

  const size_t BUF = ((size_t)N * FD * 2 + 255) & ~(size_t)255;  // one bf16 [N,128]

  // ---- common misc layout (after big buffers) ----
  auto misc_need = [&](int nbig) -> size_t {
    size_t need = (size_t)nbig * BUF;
    need += ((size_t)10 * N * 4 + 255) & ~(size_t)255;   // degf
    need += 512;                                          // biasf
    need += 256;                                          // flags
    need += 1024;                                         // bsum
    need += (((size_t)(N + 1) * 4 + 255) & ~(size_t)255) * 2;  // rpA, rpT
    need += (((size_t)N * 4 + 255) & ~(size_t)255) * 2;        // curT, cntT
    need += ((size_t)nnz * 4 + 255) & ~(size_t)255;      // tSrc
    need += ((size_t)nnz * 4 + 255) & ~(size_t)255;      // tValF
    need += ((size_t)nnz * 4 + 255) & ~(size_t)255;      // aCol32
    need += ((size_t)nnz * 4 + 255) & ~(size_t)255;      // aValF
    return need;
  };
  size_t needA = misc_need(8);
  size_t needB = misc_need(2);

  int pathA = (ws_size >= needA) ? 1 : 0;
  if (!pathA && ws_size < needB) {
    fill_k<<<(out_size + 255) / 256, 256, 0, stream>>>((unsigned short*)d_out, out_size);
    return;
  }

  int nbig = pathA ? 8 : 2;
  char* p = (char*)d_ws;
  char* bufs[8];
  for (int i = 0; i < 8; ++i) bufs[i] = (i < nbig) ? (p + (size_t)i * BUF) : nullptr;
  char* q = p + (size_t)nbig * BUF;
  auto take = [&](size_t bytes) -> char* {
    char* r = q;
    q += (bytes + 255) & ~(size_t)255;
    return r;
  };
  float* degf  = (float*)take((size_t)10 * N * 4);
  float* biasf = (float*)take(512);
  int*   flags = (int*)take(256);
  int*   bsum  = (int*)take(1024);
  int* rpA  = (int*)take((size_t)(N + 1) * 4);
  int* rpT  = (int*)take((size_t)(N + 1) * 4);
  int* curT = (int*)take((size_t)N * 4);
  int* cntT = (int*)take((size_t)N * 4);
  int* tSrc = (int*)take((size_t)nnz * 4);
  float* tValF = (float*)take((size_t)nnz * 4);
  int* aCol32 = (int*)take((size_t)nnz * 4);
  float* aValF = (float*)take((size_t)nnz * 4);

  float* u1 = degf;
  float* v1 = degf + N;
  float* e1 = degf + 2 * N;
  float* s1 = degf + 6 * N;
  float* s2 = degf + 7 * N;
  float* s3 = degf + 8 * N;
  float* s4 = degf + 9 * N;

  int eb = (nnz + 255) / 256;
  int nb = (N + 255) / 256;

  // ---- common setup ----
  detect_k<<<1, 256, 0, stream>>>(x, a_cols, flags);
  hipMemsetAsync(degf, 0, (size_t)6 * N * 4, stream);
  hipMemsetAsync(cntT, 0, (size_t)N * 4, stream);
  hist_k<<<eb, 256, 0, stream>>>(a_rows, a_cols, a_vals, nnz, u1, v1, cntT, flags);
  scanA_k<<<nb, 256, 0, stream>>>(cntT, N, bsum);
  scanB_k<<<1, 256, 0, stream>>>(bsum, nb, rpT + N);
  scanC_k<<<nb, 256, 0, stream>>>(cntT, N, bsum, rpT, curT);
  bsearch_k<<<(N + 256) / 256, 256, 0, stream>>>(a_rows, nnz, N, rpA, flags);
  scatter_k<<<eb, 256, 0, stream>>>(a_rows, a_cols, a_vals, nnz, curT, tSrc, tValF, flags);
  deg2_k<<<eb, 256, 0, stream>>>(a_rows, a_cols, a_vals, nnz, u1, v1,
                                 e1, degf + 3 * N, degf + 4 * N, degf + 5 * N, flags);
  rsqrt_k<<<(4 * N + 255) / 256, 256, 0, stream>>>(e1, s1, 4 * N);
  bias_k<<<1, FD, 0, stream>>>(b_sd, b_ds, b0, b1, b2, b3, biasf, flags);

  int sg = (N + 3) / 4;
  int gg = (N + 63) / 64;

  if (pathA) {
    cvtav_k<<<eb, 256, 0, stream>>>(a_cols, a_vals, nnz, aCol32, aValF, flags);
    __hip_bfloat16* xb = (__hip_bfloat16*)bufs[0];
    cvtx_k<<<(N * FD / 4 + 255) / 256, 256, 0, stream>>>(x, xb, N * FD, flags);

    __hip_bfloat16* t2 = (__hip_bfloat16*)bufs[1];
    __hip_bfloat16* g3 = (__hip_bfloat16*)bufs[2];
    __hip_bfloat16* g6 = (__hip_bfloat16*)bufs[3];
    __hip_bfloat16* t1 = (__hip_bfloat16*)bufs[4];
    __hip_bfloat16* g4 = (__hip_bfloat16*)bufs[5];
    __hip_bfloat16* g5 = (__hip_bfloat16*)bufs[6];
    __hip_bfloat16* y3 = (__hip_bfloat16*)bufs[7];
    __hip_bfloat16* y5 = (__hip_bfloat16*)bufs[2];  // g3 dead after y3
    __hip_bfloat16* y4 = (__hip_bfloat16*)bufs[0];  // xb dead after first hops
    __hip_bfloat16* y6 = (__hip_bfloat16*)bufs[5];  // g4 dead after y4

    // first hops (fused 3-output; share x gathers)
    fh_k<<<sg, 128, 0, stream>>>(rpT, tSrc, tValF, xb, t2, g3, g6, s1, s3, N, nnz);
    fh_k<<<sg, 128, 0, stream>>>(rpA, aCol32, aValF, xb, t1, g4, g5, s2, s4, N, nnz);
    // second hops
    sh_k<<<sg, 128, 0, stream>>>(rpA, aCol32, aValF, g3, y3, s1, N, nnz);
    sh_k<<<sg, 128, 0, stream>>>(rpT, tSrc, tValF, g4, y4, s2, N, nnz);
    sh_k<<<sg, 128, 0, stream>>>(rpA, aCol32, aValF, g5, y5, s3, N, nnz);
    sh_k<<<sg, 128, 0, stream>>>(rpT, tSrc, tValF, g6, y6, s4, N, nnz);

    G6 args;
    args.y[0] = t1; args.w[0] = w_sd;
    args.y[1] = t2; args.w[1] = w_ds;
    args.y[2] = y3; args.w[2] = w0;
    args.y[3] = y4; args.w[3] = w1;
    args.y[4] = y5; args.w[4] = w2;
    args.y[5] = y6; args.w[5] = w3;
    gemm6_k<<<gg, 256, 0, stream>>>(args, biasf, d_out, N, flags);
  } else {
    // Path B: round-4 proven sequence (fast scan already applied above)
    __hip_bfloat16* Yb = (__hip_bfloat16*)bufs[0];
    __hip_bfloat16* gb = (__hip_bfloat16*)bufs[1];
    spmm_k<<<sg, 128, 0, stream>>>(rpA, a_cols, 1, a_vals, 0, x, 1, Yb, N, nnz, nullptr, nullptr, flags);
    gemm_k<<<gg, 256, 0, stream>>>(Yb, w_sd, biasf, nullptr, d_out, N, flags);
    spmm_k<<<sg, 128, 0, stream>>>(rpT, tSrc, 0, tValF, 1, x, 1, Yb, N, nnz, nullptr, nullptr, flags);
    gemm_k<<<gg, 256, 0, stream>>>(Yb, w_ds, nullptr, d_out, d_out, N, flags);
    spmm_k<<<sg, 128, 0, stream>>>(rpT, tSrc, 0, tValF, 1, x, 1, gb, N, nnz, s1, nullptr, flags);
    spmm_k<<<sg, 128, 0, stream>>>(rpA, a_cols, 1, a_vals, 0, gb, 0, Yb, N, nnz, nullptr, s1, flags);
    gemm_k<<<gg, 256, 0, stream>>>(Yb, w0, nullptr, d_out, d_out, N, flags);
    spmm_k<<<sg, 128, 0, stream>>>(rpA, a_cols, 1, a_vals, 0, x, 1, gb, N, nnz, s2, nullptr, flags);
    spmm_k<<<sg, 128, 0, stream>>>(rpT, tSrc, 0, tValF, 1, gb, 0, Yb, N, nnz, nullptr, s2, flags);
    gemm_k<<<gg, 256, 0, stream>>>(Yb, w1, nullptr, d_out, d_out, N, flags);
    spmm_k<<<sg, 128, 0, stream>>>(rpA, a_cols, 1, a_vals, 0, x, 1, gb, N, nnz, s4, nullptr, flags);
    spmm_k<<<sg, 128, 0, stream>>>(rpA, a_cols, 1, a_vals, 0, gb, 0, Yb, N, nnz, nullptr, s3, flags);
    gemm_k<<<gg, 256, 0, stream>>>(Yb, w2, nullptr, d_out, d_out, N, flags);
    spmm_k<<<sg, 128, 0, stream>>>(rpT, tSrc, 0, tValF, 1, x, 1, gb, N, nnz, s3, nullptr, flags);
    spmm_k<<<sg, 128, 0, stream>>>(rpT, tSrc, 0, tValF, 1, gb, 0, Yb, N, nnz, nullptr, s4, flags);
    gemm_k<<<gg, 256, 0, stream>>>(Yb, w3, nullptr, d_out, d_out, N, flags);
  }
}

// Round 6
// 651.160 us; speedup vs baseline: 2.0925x; 1.3262x over previous
//
#include <hip/hip_runtime.h>
#include <hip/hip_bf16.h>

#define FD 128

typedef __attribute__((ext_vector_type(8))) short bf16x8;
typedef __attribute__((ext_vector_type(4))) float f32x4;

__device__ __forceinline__ float bfu2f(unsigned short u) {
  return __uint_as_float(((unsigned int)u) << 16);
}
__device__ __forceinline__ float b2f(__hip_bfloat16 v) { return __bfloat162float(v); }

// flag-dispatched external loads: ff=1 -> fp32, ff=0 -> bf16 ; fi=1 -> int64
__device__ __forceinline__ float ldf(const void* p, int i, int ff) {
  return ff ? ((const float*)p)[i] : b2f(((const __hip_bfloat16*)p)[i]);
}
__device__ __forceinline__ int ldi(const void* p, int i, int fi) {
  return fi ? (int)((const long long*)p)[i] : ((const int*)p)[i];
}

// ---------------- dtype detection ----------------
__global__ void detect_k(const void* x, const void* cols, int* flags) {
  __shared__ int cnt[2];
  if (threadIdx.x < 2) cnt[threadIdx.x] = 0;
  __syncthreads();
  const unsigned short* xu = (const unsigned short*)x;
  int big = 0;
  for (int i = threadIdx.x; i < 1024; i += 256) {
    int e = (xu[i] >> 7) & 0xFF;
    if (e >= 0x90) big++;
  }
  if (big) atomicAdd(&cnt[0], big);
  const int* ci = (const int*)cols;
  int zeros = 0;
  for (int i = threadIdx.x; i < 128; i += 256)
    if ((i & 1) && ci[i] == 0) zeros++;
  if (zeros) atomicAdd(&cnt[1], zeros);
  __syncthreads();
  if (threadIdx.x == 0) {
    flags[0] = (cnt[0] > 16) ? 1 : 0;
    flags[1] = (cnt[1] >= 32) ? 1 : 0;
  }
}

// ---------------- convert edge arrays to internal int32/f32 ----------------
__global__ void cvtall_k(const void* __restrict__ rows, const void* __restrict__ cols,
                         const void* __restrict__ vals, int nnz, int n,
                         int* __restrict__ r32, int* __restrict__ c32,
                         float* __restrict__ vf, const int* flags) {
  int ff = flags[0], fi = flags[1];
  int i = blockIdx.x * 256 + threadIdx.x;
  if (i >= nnz) return;
  int r = ldi(rows, i, fi);
  int c = ldi(cols, i, fi);
  if ((unsigned)r >= (unsigned)n) r = 0;
  if ((unsigned)c >= (unsigned)n) c = 0;
  r32[i] = r;
  c32[i] = c;
  vf[i] = ldf(vals, i, ff);
}

// ---------------- setup kernels (int32/f32 inputs) ----------------
__global__ void hist_k(const int* __restrict__ r, const int* __restrict__ c,
                       const float* __restrict__ v, int nnz,
                       float* u1, float* v1, int* cntT) {
  int i = blockIdx.x * 256 + threadIdx.x;
  if (i >= nnz) return;
  float vv = v[i];
  atomicAdd(&u1[r[i]], vv);
  atomicAdd(&v1[c[i]], vv);
  atomicAdd(&cntT[c[i]], 1);
}

// ---- parallel 3-pass scan ----
__global__ void scanA_k(const int* __restrict__ cnt, int n, int* bsum) {
  __shared__ int sh[256];
  int t = threadIdx.x;
  int i = blockIdx.x * 256 + t;
  sh[t] = (i < n) ? cnt[i] : 0;
  __syncthreads();
  for (int d = 128; d > 0; d >>= 1) {
    if (t < d) sh[t] += sh[t + d];
    __syncthreads();
  }
  if (t == 0) bsum[blockIdx.x] = sh[0];
}

__global__ void scanB_k(int* bsum, int nb, int* rpTail) {
  __shared__ int sh[256];
  int t = threadIdx.x;
  int v = (t < nb) ? bsum[t] : 0;
  sh[t] = v;
  __syncthreads();
  int val = v;
  for (int d = 1; d < 256; d <<= 1) {
    int add = (t >= d) ? sh[t - d] : 0;
    __syncthreads();
    val += add;
    sh[t] = val;
    __syncthreads();
  }
  if (t < nb) bsum[t] = val - v;
  if (t == 255) *rpTail = val;
}

__global__ void scanC_k(const int* __restrict__ cnt, int n, const int* __restrict__ bsum,
                        int* rp, int* cur) {
  __shared__ int sh[256];
  int t = threadIdx.x;
  int i = blockIdx.x * 256 + t;
  int v = (i < n) ? cnt[i] : 0;
  sh[t] = v;
  __syncthreads();
  int val = v;
  for (int d = 1; d < 256; d <<= 1) {
    int add = (t >= d) ? sh[t - d] : 0;
    __syncthreads();
    val += add;
    sh[t] = val;
    __syncthreads();
  }
  int ex = val - v + bsum[blockIdx.x];
  if (i < n) { rp[i] = ex; cur[i] = ex; }
}

__global__ void bsearch_k(const int* __restrict__ rows, int nnz, int n, int* rpA) {
  int i = blockIdx.x * 256 + threadIdx.x;
  if (i > n) return;
  int lo = 0, hi = nnz;
  while (lo < hi) { int mid = (lo + hi) >> 1; if (rows[mid] < i) lo = mid + 1; else hi = mid; }
  rpA[i] = lo;
}

__global__ void scatter_k(const int* __restrict__ r, const int* __restrict__ c,
                          const float* __restrict__ v, int nnz,
                          int* cur, int* tSrc, float* tVal) {
  int i = blockIdx.x * 256 + threadIdx.x;
  if (i >= nnz) return;
  int p = atomicAdd(&cur[c[i]], 1);
  if ((unsigned)p >= (unsigned)nnz) return;
  tSrc[p] = r[i];
  tVal[p] = v[i];
}

__global__ void deg2_k(const int* __restrict__ r, const int* __restrict__ c,
                       const float* __restrict__ v, int nnz,
                       const float* __restrict__ u1, const float* __restrict__ v1,
                       float* e1, float* e2, float* e3, float* e4) {
  int i = blockIdx.x * 256 + threadIdx.x;
  if (i >= nnz) return;
  int ri = r[i], ci = c[i];
  float vv = v[i];
  atomicAdd(&e1[ri], vv * v1[ci]);
  atomicAdd(&e3[ri], vv * u1[ci]);
  atomicAdd(&e2[ci], vv * u1[ri]);
  atomicAdd(&e4[ci], vv * v1[ri]);
}

__global__ void rsqrt_k(const float* __restrict__ e, float* __restrict__ s, int n) {
  int i = blockIdx.x * 256 + threadIdx.x;
  if (i >= n) return;
  float x = e[i];
  s[i] = (x > 0.f) ? rsqrtf(x) : 0.f;
}

__global__ void bias_k(const void* a, const void* b, const void* c, const void* d,
                       const void* e, const void* f, float* bias, const int* flags) {
  int ff = flags[0];
  int i = threadIdx.x;
  bias[i] = 0.5f * (ldf(a, i, ff) + ldf(b, i, ff) + ldf(c, i, ff)
                  + ldf(d, i, ff) + ldf(e, i, ff) + ldf(f, i, ff));
}

__global__ void fill_k(unsigned short* o, int n) {
  int i = blockIdx.x * 256 + threadIdx.x;
  if (i < n) o[i] = 0x3E80;
}

// x -> internal bf16
__global__ void cvtx_k(const void* __restrict__ x, __hip_bfloat16* __restrict__ xb,
                       int n, const int* flags) {
  int ff = flags[0];
  int i = (blockIdx.x * 256 + threadIdx.x) * 4;
  if (i + 3 >= n) {
    for (int k = i; k < n; ++k) xb[k] = __float2bfloat16(ldf(x, k, ff));
    return;
  }
  xb[i + 0] = __float2bfloat16(ldf(x, i + 0, ff));
  xb[i + 1] = __float2bfloat16(ldf(x, i + 1, ff));
  xb[i + 2] = __float2bfloat16(ldf(x, i + 2, ff));
  xb[i + 3] = __float2bfloat16(ldf(x, i + 3, ff));
}

// W segs -> transposed bf16 Wt[n=128][K=768] (seg s at cols s*128..)
struct W6p { const void* w[6]; };
__global__ void wt_k(W6p ws, __hip_bfloat16* __restrict__ Wt, const int* flags) {
  int ff = flags[0];
  int idx = blockIdx.x * 256 + threadIdx.x;
  if (idx >= 6 * 16384) return;
  int seg = idx >> 14;
  int kn = idx & 16383;
  int k = kn >> 7, nn = kn & 127;
  Wt[(size_t)nn * 768 + seg * 128 + k] = __float2bfloat16(ldf(ws.w[seg], kn, ff));
}

// ---------------- fused first hop: wave-per-row, 2 edges/iter, ushort4 lanes ----
// ot = M.xb ; oa = M.(sA.xb) ; ob = M.(sB.xb)
__global__ __launch_bounds__(256) void fh3_k(
    const int* __restrict__ rp, const int* __restrict__ ci, const float* __restrict__ cv,
    const __hip_bfloat16* __restrict__ xb,
    __hip_bfloat16* __restrict__ ot, __hip_bfloat16* __restrict__ oa,
    __hip_bfloat16* __restrict__ ob,
    const float* __restrict__ sA, const float* __restrict__ sB, int n) {
  int wave = threadIdx.x >> 6;
  int lane = threadIdx.x & 63;
  int half = lane >> 5;
  int li = lane & 31;
  int r = blockIdx.x * 4 + wave;
  if (r >= n) return;
  int s = rp[r], e = rp[r + 1];
  float t0 = 0, t1 = 0, t2 = 0, t3 = 0;
  float a0 = 0, a1 = 0, a2 = 0, a3 = 0;
  float b0 = 0, b1 = 0, b2 = 0, b3 = 0;
  for (int j = s + half; j < e; j += 2) {
    int c = ci[j];
    float v = cv[j];
    float va = v * sA[c];
    float vb = v * sB[c];
    ushort4 u = *(const ushort4*)((const unsigned short*)xb + (size_t)c * FD + li * 4);
    float x0 = bfu2f(u.x), x1 = bfu2f(u.y), x2 = bfu2f(u.z), x3 = bfu2f(u.w);
    t0 = fmaf(v, x0, t0); t1 = fmaf(v, x1, t1); t2 = fmaf(v, x2, t2); t3 = fmaf(v, x3, t3);
    a0 = fmaf(va, x0, a0); a1 = fmaf(va, x1, a1); a2 = fmaf(va, x2, a2); a3 = fmaf(va, x3, a3);
    b0 = fmaf(vb, x0, b0); b1 = fmaf(vb, x1, b1); b2 = fmaf(vb, x2, b2); b3 = fmaf(vb, x3, b3);
  }
  t0 += __shfl_xor(t0, 32); t1 += __shfl_xor(t1, 32);
  t2 += __shfl_xor(t2, 32); t3 += __shfl_xor(t3, 32);
  a0 += __shfl_xor(a0, 32); a1 += __shfl_xor(a1, 32);
  a2 += __shfl_xor(a2, 32); a3 += __shfl_xor(a3, 32);
  b0 += __shfl_xor(b0, 32); b1 += __shfl_xor(b1, 32);
  b2 += __shfl_xor(b2, 32); b3 += __shfl_xor(b3, 32);
  if (half == 0) {
    size_t off = (size_t)r * FD + li * 4;
    ushort4 o;
    o.x = __bfloat16_as_ushort(__float2bfloat16(t0));
    o.y = __bfloat16_as_ushort(__float2bfloat16(t1));
    o.z = __bfloat16_as_ushort(__float2bfloat16(t2));
    o.w = __bfloat16_as_ushort(__float2bfloat16(t3));
    *(ushort4*)((unsigned short*)ot + off) = o;
    o.x = __bfloat16_as_ushort(__float2bfloat16(a0));
    o.y = __bfloat16_as_ushort(__float2bfloat16(a1));
    o.z = __bfloat16_as_ushort(__float2bfloat16(a2));
    o.w = __bfloat16_as_ushort(__float2bfloat16(a3));
    *(ushort4*)((unsigned short*)oa + off) = o;
    o.x = __bfloat16_as_ushort(__float2bfloat16(b0));
    o.y = __bfloat16_as_ushort(__float2bfloat16(b1));
    o.z = __bfloat16_as_ushort(__float2bfloat16(b2));
    o.w = __bfloat16_as_ushort(__float2bfloat16(b3));
    *(ushort4*)((unsigned short*)ob + off) = o;
  }
}

// ---------------- fused second hop: 2 sources, 2 outputs, shared indices ----
__global__ __launch_bounds__(256) void sh2_k(
    const int* __restrict__ rp, const int* __restrict__ ci, const float* __restrict__ cv,
    const __hip_bfloat16* __restrict__ ga, const __hip_bfloat16* __restrict__ gb,
    __hip_bfloat16* __restrict__ ya, __hip_bfloat16* __restrict__ yb,
    const float* __restrict__ rsa, const float* __restrict__ rsb, int n) {
  int wave = threadIdx.x >> 6;
  int lane = threadIdx.x & 63;
  int half = lane >> 5;
  int li = lane & 31;
  int r = blockIdx.x * 4 + wave;
  if (r >= n) return;
  int s = rp[r], e = rp[r + 1];
  float a0 = 0, a1 = 0, a2 = 0, a3 = 0;
  float b0 = 0, b1 = 0, b2 = 0, b3 = 0;
  for (int j = s + half; j < e; j += 2) {
    int c = ci[j];
    float v = cv[j];
    size_t off = (size_t)c * FD + li * 4;
    ushort4 u = *(const ushort4*)((const unsigned short*)ga + off);
    ushort4 w = *(const ushort4*)((const unsigned short*)gb + off);
    a0 = fmaf(v, bfu2f(u.x), a0); a1 = fmaf(v, bfu2f(u.y), a1);
    a2 = fmaf(v, bfu2f(u.z), a2); a3 = fmaf(v, bfu2f(u.w), a3);
    b0 = fmaf(v, bfu2f(w.x), b0); b1 = fmaf(v, bfu2f(w.y), b1);
    b2 = fmaf(v, bfu2f(w.z), b2); b3 = fmaf(v, bfu2f(w.w), b3);
  }
  a0 += __shfl_xor(a0, 32); a1 += __shfl_xor(a1, 32);
  a2 += __shfl_xor(a2, 32); a3 += __shfl_xor(a3, 32);
  b0 += __shfl_xor(b0, 32); b1 += __shfl_xor(b1, 32);
  b2 += __shfl_xor(b2, 32); b3 += __shfl_xor(b3, 32);
  if (half == 0) {
    float ra = rsa[r], rb = rsb[r];
    size_t off = (size_t)r * FD + li * 4;
    ushort4 o;
    o.x = __bfloat16_as_ushort(__float2bfloat16(a0 * ra));
    o.y = __bfloat16_as_ushort(__float2bfloat16(a1 * ra));
    o.z = __bfloat16_as_ushort(__float2bfloat16(a2 * ra));
    o.w = __bfloat16_as_ushort(__float2bfloat16(a3 * ra));
    *(ushort4*)((unsigned short*)ya + off) = o;
    o.x = __bfloat16_as_ushort(__float2bfloat16(b0 * rb));
    o.y = __bfloat16_as_ushort(__float2bfloat16(b1 * rb));
    o.z = __bfloat16_as_ushort(__float2bfloat16(b2 * rb));
    o.w = __bfloat16_as_ushort(__float2bfloat16(b3 * rb));
    *(ushort4*)((unsigned short*)yb + off) = o;
  }
}

// ---------------- MFMA fused GEMM: out = 0.5*sum_i Yi@Wi + bias ----------------
struct Y6 { const unsigned short* y[6]; };

__global__ __launch_bounds__(256) void gemm6m_k(
    Y6 ys, const unsigned short* __restrict__ Wt, const float* __restrict__ bias,
    void* __restrict__ outp, int M, const int* flags) {
  int ff = flags[0];
  int wave = threadIdx.x >> 6;
  int lane = threadIdx.x & 63;
  int m = lane & 15, q = lane >> 4;
  int r0 = blockIdx.x * 64 + wave * 16;
  f32x4 acc[8];
#pragma unroll
  for (int nt = 0; nt < 8; ++nt) acc[nt] = (f32x4){0.f, 0.f, 0.f, 0.f};
  int rowA = r0 + m;
  bool okA = rowA < M;
  for (int seg = 0; seg < 6; ++seg) {
    const unsigned short* Y = ys.y[seg];
#pragma unroll
    for (int kc = 0; kc < 4; ++kc) {
      bf16x8 af = {0, 0, 0, 0, 0, 0, 0, 0};
      if (okA) af = *(const bf16x8*)(Y + (size_t)rowA * FD + kc * 32 + q * 8);
#pragma unroll
      for (int nt = 0; nt < 8; ++nt) {
        bf16x8 bf = *(const bf16x8*)(Wt + (size_t)(nt * 16 + m) * 768 + seg * 128 + kc * 32 + q * 8);
        acc[nt] = __builtin_amdgcn_mfma_f32_16x16x32_bf16(af, bf, acc[nt], 0, 0, 0);
      }
    }
  }
#pragma unroll
  for (int nt = 0; nt < 8; ++nt) {
    int col = nt * 16 + m;
    float bv = bias[col];
#pragma unroll
    for (int rg = 0; rg < 4; ++rg) {
      int grow = r0 + q * 4 + rg;
      if (grow >= M) continue;
      float v = 0.5f * acc[nt][rg] + bv;
      if (ff) ((float*)outp)[(size_t)grow * FD + col] = v;
      else ((unsigned short*)outp)[(size_t)grow * FD + col] =
          __bfloat16_as_ushort(__float2bfloat16(v));
    }
  }
}

// ---------------- legacy Path B kernels (proven round 4) ----------------
__global__ __launch_bounds__(128) void spmm_k(
    const int* __restrict__ rp, const void* __restrict__ ci, int cif,
    const void* __restrict__ cv, int cvf,
    const void* __restrict__ x, int xf, __hip_bfloat16* __restrict__ y,
    int n, int nnzMax,
    const float* __restrict__ cscale, const float* __restrict__ rscale,
    const int* flags) {
  int ff = flags[0], fi = flags[1];
  int vf = cvf ? 1 : ff;
  int iw = cif ? fi : 0;
  int xw = xf ? ff : 0;
  const int t = threadIdx.x;
  int r0 = blockIdx.x * 4;
  int rend = min(r0 + 4, n);
  for (int r = r0; r < rend; ++r) {
    int s = rp[r], e = rp[r + 1];
    s = max(0, min(s, nnzMax));
    e = max(s, min(e, nnzMax));
    float acc = 0.f;
    for (int j = s; j < e; ++j) {
      int c = ldi(ci, j, iw);
      if ((unsigned)c >= (unsigned)n) c = 0;
      float v = (vf ? ((const float*)cv)[j] : b2f(((const __hip_bfloat16*)cv)[j]));
      if (cscale) v *= cscale[c];
      float xv = xw ? ((const float*)x)[c * FD + t]
                    : b2f(((const __hip_bfloat16*)x)[c * FD + t]);
      acc = fmaf(v, xv, acc);
    }
    if (rscale) acc *= rscale[r];
    y[r * FD + t] = __float2bfloat16(acc);
  }
}

__global__ __launch_bounds__(256) void gemm_k(
    const __hip_bfloat16* __restrict__ Y, const void* __restrict__ W,
    const float* __restrict__ bias, const void* __restrict__ accin,
    void* __restrict__ outp, int M, const int* flags) {
  int ff = flags[0];
  __shared__ __align__(16) float Wl[32 * 128];
  __shared__ __align__(16) float Yl[64 * 36];
  const int t = threadIdx.x;
  const int row0 = blockIdx.x * 64;
  const int c4 = (t & 31) * 4;
  const int r8 = (t >> 5) * 8;
  const int rs = t >> 3;
  const int q = t & 7;
  float acc[8][4];
#pragma unroll
  for (int m = 0; m < 8; ++m)
#pragma unroll
    for (int j = 0; j < 4; ++j) acc[m][j] = 0.f;
  for (int kc = 0; kc < 4; ++kc) {
    if (ff) {
      const float4* Wg4 = (const float4*)((const float*)W + kc * 32 * 128);
#pragma unroll
      for (int i = 0; i < 4; ++i)
        *(float4*)(Wl + (t + i * 256) * 4) = Wg4[t + i * 256];
    } else {
      const ushort4* Wg4 = (const ushort4*)((const unsigned short*)W + kc * 32 * 128);
#pragma unroll
      for (int i = 0; i < 4; ++i) {
        ushort4 u = Wg4[t + i * 256];
        int base = (t + i * 256) * 4;
        Wl[base + 0] = bfu2f(u.x);
        Wl[base + 1] = bfu2f(u.y);
        Wl[base + 2] = bfu2f(u.z);
        Wl[base + 3] = bfu2f(u.w);
      }
    }
#pragma unroll
    for (int i = 0; i < 2; ++i) {
      int rr = rs + i * 32;
      int grow = row0 + rr;
      ushort4 u = make_ushort4(0, 0, 0, 0);
      if (grow < M)
        u = *(const ushort4*)((const unsigned short*)Y + grow * FD + kc * 32 + q * 4);
      float* yd = Yl + rr * 36 + q * 4;
      yd[0] = bfu2f(u.x); yd[1] = bfu2f(u.y); yd[2] = bfu2f(u.z); yd[3] = bfu2f(u.w);
    }
    __syncthreads();
#pragma unroll
    for (int kk = 0; kk < 32; kk += 4) {
      float4 w0 = *(const float4*)(Wl + (kk + 0) * 128 + c4);
      float4 w1 = *(const float4*)(Wl + (kk + 1) * 128 + c4);
      float4 w2 = *(const float4*)(Wl + (kk + 2) * 128 + c4);
      float4 w3 = *(const float4*)(Wl + (kk + 3) * 128 + c4);
#pragma unroll
      for (int m = 0; m < 8; ++m) {
        float4 yv = *(const float4*)(Yl + (r8 + m) * 36 + kk);
        acc[m][0] = fmaf(yv.x, w0.x, acc[m][0]);
        acc[m][1] = fmaf(yv.x, w0.y, acc[m][1]);
        acc[m][2] = fmaf(yv.x, w0.z, acc[m][2]);
        acc[m][3] = fmaf(yv.x, w0.w, acc[m][3]);
        acc[m][0] = fmaf(yv.y, w1.x, acc[m][0]);
        acc[m][1] = fmaf(yv.y, w1.y, acc[m][1]);
        acc[m][2] = fmaf(yv.y, w1.z, acc[m][2]);
        acc[m][3] = fmaf(yv.y, w1.w, acc[m][3]);
        acc[m][0] = fmaf(yv.z, w2.x, acc[m][0]);
        acc[m][1] = fmaf(yv.z, w2.y, acc[m][1]);
        acc[m][2] = fmaf(yv.z, w2.z, acc[m][2]);
        acc[m][3] = fmaf(yv.z, w2.w, acc[m][3]);
        acc[m][0] = fmaf(yv.w, w3.x, acc[m][0]);
        acc[m][1] = fmaf(yv.w, w3.y, acc[m][1]);
        acc[m][2] = fmaf(yv.w, w3.z, acc[m][2]);
        acc[m][3] = fmaf(yv.w, w3.w, acc[m][3]);
      }
    }
    __syncthreads();
  }
  float4 b4 = make_float4(0.f, 0.f, 0.f, 0.f);
  if (bias) b4 = *(const float4*)(bias + c4);
#pragma unroll
  for (int m = 0; m < 8; ++m) {
    int grow = row0 + r8 + m;
    if (grow >= M) continue;
    float4 rv;
    rv.x = 0.5f * acc[m][0] + b4.x;
    rv.y = 0.5f * acc[m][1] + b4.y;
    rv.z = 0.5f * acc[m][2] + b4.z;
    rv.w = 0.5f * acc[m][3] + b4.w;
    if (accin) {
      if (ff) {
        float4 o = *(const float4*)((const float*)accin + grow * FD + c4);
        rv.x += o.x; rv.y += o.y; rv.z += o.z; rv.w += o.w;
      } else {
        ushort4 o = *(const ushort4*)((const unsigned short*)accin + grow * FD + c4);
        rv.x += bfu2f(o.x); rv.y += bfu2f(o.y); rv.z += bfu2f(o.z); rv.w += bfu2f(o.w);
      }
    }
    if (ff) {
      *(float4*)((float*)outp + grow * FD + c4) = rv;
    } else {
      ushort4 so;
      so.x = __bfloat16_as_ushort(__float2bfloat16(rv.x));
      so.y = __bfloat16_as_ushort(__float2bfloat16(rv.y));
      so.z = __bfloat16_as_ushort(__float2bfloat16(rv.z));
      so.w = __bfloat16_as_ushort(__float2bfloat16(rv.w));
      *(ushort4*)((unsigned short*)outp + grow * FD + c4) = so;
    }
  }
}

extern "C" void kernel_launch(void* const* d_in, const int* in_sizes, int n_in,
                              void* d_out, int out_size, void* d_ws, size_t ws_size,
                              hipStream_t stream) {
  const void* x    = d_in[0];
  const void* w_sd = d_in[1];
  const void* b_sd = d_in[2];
  const void* w_ds = d_in[3];
  const void* b_ds = d_in[4];
  const void* w0   = d_in[5];
  const void* b0   = d_in[6];
  const void* w1   = d_in[7];
  const void* b1   = d_in[8];
  const void* w2   = d_in[9];
  const void* b2   = d_in[10];
  const void* w3   = d_in[11];
  const void* b3   = d_in[12];
  const void* a_rows = d_in[13];
  const void* a_cols = d_in[14];
  const void* a_vals = d_in[15];
  const int nnz = in_sizes[13];
  const int N = in_sizes[0] / FD;

  const size_t BUF = ((size_t)N * FD * 2 + 255) & ~(size_t)255;

  auto misc_need = [&](int nbig) -> size_t {
    size_t need = (size_t)nbig * BUF;
    need += ((size_t)10 * N * 4 + 255) & ~(size_t)255;          // degf
    need += 512 + 256 + 1024;                                    // biasf, flags, bsum
    need += (((size_t)(N + 1) * 4 + 255) & ~(size_t)255) * 2;   // rpA, rpT
    need += (((size_t)N * 4 + 255) & ~(size_t)255) * 2;         // curT, cntT
    need += (((size_t)nnz * 4 + 255) & ~(size_t)255) * 5;       // tSrc,tValF,aRow32,aCol32,aValF
    need += (6 * 16384 * 2 + 255) & ~(size_t)255;               // Wt
    return need;
  };
  size_t needA = misc_need(8);
  size_t needB = misc_need(2);

  int pathA = (ws_size >= needA) ? 1 : 0;
  if (!pathA && ws_size < needB) {
    fill_k<<<(out_size + 255) / 256, 256, 0, stream>>>((unsigned short*)d_out, out_size);
    return;
  }

  int nbig = pathA ? 8 : 2;
  char* p = (char*)d_ws;
  char* bufs[8];
  for (int i = 0; i < 8; ++i) bufs[i] = (i < nbig) ? (p + (size_t)i * BUF) : nullptr;
  char* q = p + (size_t)nbig * BUF;
  auto take = [&](size_t bytes) -> char* {
    char* r = q;
    q += (bytes + 255) & ~(size_t)255;
    return r;
  };
  float* degf  = (float*)take((size_t)10 * N * 4);
  float* biasf = (float*)take(512);
  int*   flags = (int*)take(256);
  int*   bsum  = (int*)take(1024);
  int* rpA  = (int*)take((size_t)(N + 1) * 4);
  int* rpT  = (int*)take((size_t)(N + 1) * 4);
  int* curT = (int*)take((size_t)N * 4);
  int* cntT = (int*)take((size_t)N * 4);
  int* tSrc = (int*)take((size_t)nnz * 4);
  float* tValF = (float*)take((size_t)nnz * 4);
  int* aRow32 = (int*)take((size_t)nnz * 4);
  int* aCol32 = (int*)take((size_t)nnz * 4);
  float* aValF = (float*)take((size_t)nnz * 4);
  __hip_bfloat16* Wt = (__hip_bfloat16*)take(6 * 16384 * 2);

  float* u1 = degf;
  float* v1 = degf + N;
  float* e1 = degf + 2 * N;
  float* s1 = degf + 6 * N;
  float* s2 = degf + 7 * N;
  float* s3 = degf + 8 * N;
  float* s4 = degf + 9 * N;

  int eb = (nnz + 255) / 256;
  int nb = (N + 255) / 256;

  detect_k<<<1, 256, 0, stream>>>(x, a_cols, flags);
  cvtall_k<<<eb, 256, 0, stream>>>(a_rows, a_cols, a_vals, nnz, N, aRow32, aCol32, aValF, flags);
  hipMemsetAsync(degf, 0, (size_t)6 * N * 4, stream);
  hipMemsetAsync(cntT, 0, (size_t)N * 4, stream);
  hist_k<<<eb, 256, 0, stream>>>(aRow32, aCol32, aValF, nnz, u1, v1, cntT);
  scanA_k<<<nb, 256, 0, stream>>>(cntT, N, bsum);
  scanB_k<<<1, 256, 0, stream>>>(bsum, nb, rpT + N);
  scanC_k<<<nb, 256, 0, stream>>>(cntT, N, bsum, rpT, curT);
  bsearch_k<<<(N + 256) / 256, 256, 0, stream>>>(aRow32, nnz, N, rpA);
  scatter_k<<<eb, 256, 0, stream>>>(aRow32, aCol32, aValF, nnz, curT, tSrc, tValF);
  deg2_k<<<eb, 256, 0, stream>>>(aRow32, aCol32, aValF, nnz, u1, v1,
                                 e1, degf + 3 * N, degf + 4 * N, degf + 5 * N);
  rsqrt_k<<<(4 * N + 255) / 256, 256, 0, stream>>>(e1, s1, 4 * N);
  bias_k<<<1, FD, 0, stream>>>(b_sd, b_ds, b0, b1, b2, b3, biasf, flags);

  int sg2 = (N + 3) / 4;
  int gg = (N + 63) / 64;

  if (pathA) {
    W6p wargs;
    wargs.w[0] = w_sd; wargs.w[1] = w_ds; wargs.w[2] = w0;
    wargs.w[3] = w1;   wargs.w[4] = w2;   wargs.w[5] = w3;
    wt_k<<<(6 * 16384 + 255) / 256, 256, 0, stream>>>(wargs, Wt, flags);

    __hip_bfloat16* xb = (__hip_bfloat16*)bufs[0];
    cvtx_k<<<(N * FD / 4 + 255) / 256, 256, 0, stream>>>(x, xb, N * FD, flags);

    __hip_bfloat16* t2 = (__hip_bfloat16*)bufs[1];
    __hip_bfloat16* g3 = (__hip_bfloat16*)bufs[2];
    __hip_bfloat16* g6 = (__hip_bfloat16*)bufs[3];
    __hip_bfloat16* t1 = (__hip_bfloat16*)bufs[4];
    __hip_bfloat16* g4 = (__hip_bfloat16*)bufs[5];
    __hip_bfloat16* g5 = (__hip_bfloat16*)bufs[6];
    __hip_bfloat16* y3 = (__hip_bfloat16*)bufs[7];
    __hip_bfloat16* y5 = (__hip_bfloat16*)bufs[0];  // xb dead after first hops
    __hip_bfloat16* y4 = (__hip_bfloat16*)bufs[2];  // g3 dead after shA
    __hip_bfloat16* y6 = (__hip_bfloat16*)bufs[6];  // g5 dead after shA

    fh3_k<<<sg2, 256, 0, stream>>>(rpT, tSrc, tValF, xb, t2, g3, g6, s1, s3, N);
    fh3_k<<<sg2, 256, 0, stream>>>(rpA, aCol32, aValF, xb, t1, g4, g5, s2, s4, N);
    sh2_k<<<sg2, 256, 0, stream>>>(rpA, aCol32, aValF, g3, g5, y3, y5, s1, s3, N);
    sh2_k<<<sg2, 256, 0, stream>>>(rpT, tSrc, tValF, g4, g6, y4, y6, s2, s4, N);

    Y6 yargs;
    yargs.y[0] = (const unsigned short*)t1;
    yargs.y[1] = (const unsigned short*)t2;
    yargs.y[2] = (const unsigned short*)y3;
    yargs.y[3] = (const unsigned short*)y4;
    yargs.y[4] = (const unsigned short*)y5;
    yargs.y[5] = (const unsigned short*)y6;
    gemm6m_k<<<gg, 256, 0, stream>>>(yargs, (const unsigned short*)Wt, biasf, d_out, N, flags);
  } else {
    __hip_bfloat16* Yb = (__hip_bfloat16*)bufs[0];
    __hip_bfloat16* gb = (__hip_bfloat16*)bufs[1];
    spmm_k<<<sg2, 128, 0, stream>>>(rpA, a_cols, 1, a_vals, 0, x, 1, Yb, N, nnz, nullptr, nullptr, flags);
    gemm_k<<<gg, 256, 0, stream>>>(Yb, w_sd, biasf, nullptr, d_out, N, flags);
    spmm_k<<<sg2, 128, 0, stream>>>(rpT, tSrc, 0, tValF, 1, x, 1, Yb, N, nnz, nullptr, nullptr, flags);
    gemm_k<<<gg, 256, 0, stream>>>(Yb, w_ds, nullptr, d_out, d_out, N, flags);
    spmm_k<<<sg2, 128, 0, stream>>>(rpT, tSrc, 0, tValF, 1, x, 1, gb, N, nnz, s1, nullptr, flags);
    spmm_k<<<sg2, 128, 0, stream>>>(rpA, a_cols, 1, a_vals, 0, gb, 0, Yb, N, nnz, nullptr, s1, flags);
    gemm_k<<<gg, 256, 0, stream>>>(Yb, w0, nullptr, d_out, d_out, N, flags);
    spmm_k<<<sg2, 128, 0, stream>>>(rpA, a_cols, 1, a_vals, 0, x, 1, gb, N, nnz, s2, nullptr, flags);
    spmm_k<<<sg2, 128, 0, stream>>>(rpT, tSrc, 0, tValF, 1, gb, 0, Yb, N, nnz, nullptr, s2, flags);
    gemm_k<<<gg, 256, 0, stream>>>(Yb, w1, nullptr, d_out, d_out, N, flags);
    spmm_k<<<sg2, 128, 0, stream>>>(rpA, a_cols, 1, a_vals, 0, x, 1, gb, N, nnz, s4, nullptr, flags);
    spmm_k<<<sg2, 128, 0, stream>>>(rpA, a_cols, 1, a_vals, 0, gb, 0, Yb, N, nnz, nullptr, s3, flags);
    gemm_k<<<gg, 256, 0, stream>>>(Yb, w2, nullptr, d_out, d_out, N, flags);
    spmm_k<<<sg2, 128, 0, stream>>>(rpT, tSrc, 0, tValF, 1, x, 1, gb, N, nnz, s3, nullptr, flags);
    spmm_k<<<sg2, 128, 0, stream>>>(rpT, tSrc, 0, tValF, 1, gb, 0, Yb, N, nnz, nullptr, s4, flags);
    gemm_k<<<gg, 256, 0, stream>>>(Yb, w3, nullptr, d_out, d_out, N, flags);
  }
}

// Round 7
// 622.131 us; speedup vs baseline: 2.1901x; 1.0467x over previous
//
#include <hip/hip_runtime.h>
#include <hip/hip_bf16.h>

#define FD 128

typedef __attribute__((ext_vector_type(8))) short bf16x8;
typedef __attribute__((ext_vector_type(4))) float f32x4;

__device__ __forceinline__ float bfu2f(unsigned short u) {
  return __uint_as_float(((unsigned int)u) << 16);
}
__device__ __forceinline__ float b2f(__hip_bfloat16 v) { return __bfloat162float(v); }
__device__ __forceinline__ unsigned int pk2(float lo, float hi) {
  return (unsigned int)__bfloat16_as_ushort(__float2bfloat16(lo)) |
         ((unsigned int)__bfloat16_as_ushort(__float2bfloat16(hi)) << 16);
}

// flag-dispatched external loads: ff=1 -> fp32, ff=0 -> bf16 ; fi=1 -> int64
__device__ __forceinline__ float ldf(const void* p, int i, int ff) {
  return ff ? ((const float*)p)[i] : b2f(((const __hip_bfloat16*)p)[i]);
}
__device__ __forceinline__ int ldi(const void* p, int i, int fi) {
  return fi ? (int)((const long long*)p)[i] : ((const int*)p)[i];
}

// ---------------- dtype detection ----------------
__global__ void detect_k(const void* x, const void* cols, int* flags) {
  __shared__ int cnt[2];
  if (threadIdx.x < 2) cnt[threadIdx.x] = 0;
  __syncthreads();
  const unsigned short* xu = (const unsigned short*)x;
  int big = 0;
  for (int i = threadIdx.x; i < 1024; i += 256) {
    int e = (xu[i] >> 7) & 0xFF;
    if (e >= 0x90) big++;
  }
  if (big) atomicAdd(&cnt[0], big);
  const int* ci = (const int*)cols;
  int zeros = 0;
  for (int i = threadIdx.x; i < 128; i += 256)
    if ((i & 1) && ci[i] == 0) zeros++;
  if (zeros) atomicAdd(&cnt[1], zeros);
  __syncthreads();
  if (threadIdx.x == 0) {
    flags[0] = (cnt[0] > 16) ? 1 : 0;
    flags[1] = (cnt[1] >= 32) ? 1 : 0;
  }
}

// ---------------- convert edge arrays to internal int32/f32 ----------------
__global__ void cvtall_k(const void* __restrict__ rows, const void* __restrict__ cols,
                         const void* __restrict__ vals, int nnz, int n,
                         int* __restrict__ r32, int* __restrict__ c32,
                         float* __restrict__ vf, const int* flags) {
  int ff = flags[0], fi = flags[1];
  int i = blockIdx.x * 256 + threadIdx.x;
  if (i >= nnz) return;
  int r = ldi(rows, i, fi);
  int c = ldi(cols, i, fi);
  if ((unsigned)r >= (unsigned)n) r = 0;
  if ((unsigned)c >= (unsigned)n) c = 0;
  r32[i] = r;
  c32[i] = c;
  vf[i] = ldf(vals, i, ff);
}

// ---------------- setup kernels (int32/f32 inputs) ----------------
__global__ void hist_k(const int* __restrict__ r, const int* __restrict__ c,
                       const float* __restrict__ v, int nnz,
                       float* u1, float* v1, int* cntT) {
  int i = blockIdx.x * 256 + threadIdx.x;
  if (i >= nnz) return;
  float vv = v[i];
  atomicAdd(&u1[r[i]], vv);
  atomicAdd(&v1[c[i]], vv);
  atomicAdd(&cntT[c[i]], 1);
}

// ---- parallel 3-pass scan ----
__global__ void scanA_k(const int* __restrict__ cnt, int n, int* bsum) {
  __shared__ int sh[256];
  int t = threadIdx.x;
  int i = blockIdx.x * 256 + t;
  sh[t] = (i < n) ? cnt[i] : 0;
  __syncthreads();
  for (int d = 128; d > 0; d >>= 1) {
    if (t < d) sh[t] += sh[t + d];
    __syncthreads();
  }
  if (t == 0) bsum[blockIdx.x] = sh[0];
}

__global__ void scanB_k(int* bsum, int nb, int* rpTail) {
  __shared__ int sh[256];
  int t = threadIdx.x;
  int v = (t < nb) ? bsum[t] : 0;
  sh[t] = v;
  __syncthreads();
  int val = v;
  for (int d = 1; d < 256; d <<= 1) {
    int add = (t >= d) ? sh[t - d] : 0;
    __syncthreads();
    val += add;
    sh[t] = val;
    __syncthreads();
  }
  if (t < nb) bsum[t] = val - v;
  if (t == 255) *rpTail = val;
}

__global__ void scanC_k(const int* __restrict__ cnt, int n, const int* __restrict__ bsum,
                        int* rp, int* cur) {
  __shared__ int sh[256];
  int t = threadIdx.x;
  int i = blockIdx.x * 256 + t;
  int v = (i < n) ? cnt[i] : 0;
  sh[t] = v;
  __syncthreads();
  int val = v;
  for (int d = 1; d < 256; d <<= 1) {
    int add = (t >= d) ? sh[t - d] : 0;
    __syncthreads();
    val += add;
    sh[t] = val;
    __syncthreads();
  }
  int ex = val - v + bsum[blockIdx.x];
  if (i < n) { rp[i] = ex; cur[i] = ex; }
}

__global__ void bsearch_k(const int* __restrict__ rows, int nnz, int n, int* rpA) {
  int i = blockIdx.x * 256 + threadIdx.x;
  if (i > n) return;
  int lo = 0, hi = nnz;
  while (lo < hi) { int mid = (lo + hi) >> 1; if (rows[mid] < i) lo = mid + 1; else hi = mid; }
  rpA[i] = lo;
}

__global__ void scatter_k(const int* __restrict__ r, const int* __restrict__ c,
                          const float* __restrict__ v, int nnz,
                          int* cur, int* tSrc, float* tVal) {
  int i = blockIdx.x * 256 + threadIdx.x;
  if (i >= nnz) return;
  int p = atomicAdd(&cur[c[i]], 1);
  if ((unsigned)p >= (unsigned)nnz) return;
  tSrc[p] = r[i];
  tVal[p] = v[i];
}

__global__ void deg2_k(const int* __restrict__ r, const int* __restrict__ c,
                       const float* __restrict__ v, int nnz,
                       const float* __restrict__ u1, const float* __restrict__ v1,
                       float* e1, float* e2, float* e3, float* e4) {
  int i = blockIdx.x * 256 + threadIdx.x;
  if (i >= nnz) return;
  int ri = r[i], ci = c[i];
  float vv = v[i];
  atomicAdd(&e1[ri], vv * v1[ci]);
  atomicAdd(&e3[ri], vv * u1[ci]);
  atomicAdd(&e2[ci], vv * u1[ri]);
  atomicAdd(&e4[ci], vv * v1[ri]);
}

__global__ void rsqrt_k(const float* __restrict__ e, float* __restrict__ s, int n) {
  int i = blockIdx.x * 256 + threadIdx.x;
  if (i >= n) return;
  float x = e[i];
  s[i] = (x > 0.f) ? rsqrtf(x) : 0.f;
}

__global__ void bias_k(const void* a, const void* b, const void* c, const void* d,
                       const void* e, const void* f, float* bias, const int* flags) {
  int ff = flags[0];
  int i = threadIdx.x;
  bias[i] = 0.5f * (ldf(a, i, ff) + ldf(b, i, ff) + ldf(c, i, ff)
                  + ldf(d, i, ff) + ldf(e, i, ff) + ldf(f, i, ff));
}

__global__ void fill_k(unsigned short* o, int n) {
  int i = blockIdx.x * 256 + threadIdx.x;
  if (i < n) o[i] = 0x3E80;
}

// x -> internal bf16
__global__ void cvtx_k(const void* __restrict__ x, __hip_bfloat16* __restrict__ xb,
                       int n, const int* flags) {
  int ff = flags[0];
  int i = (blockIdx.x * 256 + threadIdx.x) * 4;
  if (i + 3 >= n) {
    for (int k = i; k < n; ++k) xb[k] = __float2bfloat16(ldf(x, k, ff));
    return;
  }
  xb[i + 0] = __float2bfloat16(ldf(x, i + 0, ff));
  xb[i + 1] = __float2bfloat16(ldf(x, i + 1, ff));
  xb[i + 2] = __float2bfloat16(ldf(x, i + 2, ff));
  xb[i + 3] = __float2bfloat16(ldf(x, i + 3, ff));
}

// W segs -> transposed bf16 Wt[n=128][K=768] (seg s at cols s*128..)
struct W6p { const void* w[6]; };
__global__ void wt_k(W6p ws, __hip_bfloat16* __restrict__ Wt, const int* flags) {
  int ff = flags[0];
  int idx = blockIdx.x * 256 + threadIdx.x;
  if (idx >= 6 * 16384) return;
  int seg = idx >> 14;
  int kn = idx & 16383;
  int k = kn >> 7, nn = kn & 127;
  Wt[(size_t)nn * 768 + seg * 128 + k] = __float2bfloat16(ldf(ws.w[seg], kn, ff));
}

// ---------------- fused first hop: wave-per-row, 4 edge slots × 16 lanes ----
// ot = M.xb ; oa = M.(sA.xb) ; ob = M.(sB.xb).  xb as uint rows (64 uints/row).
__global__ __launch_bounds__(256) void fh3_k(
    const int* __restrict__ rp, const int* __restrict__ ci, const float* __restrict__ cv,
    const unsigned int* __restrict__ xb,
    unsigned int* __restrict__ ot, unsigned int* __restrict__ oa,
    unsigned int* __restrict__ ob,
    const float* __restrict__ sA, const float* __restrict__ sB, int n) {
  int wave = threadIdx.x >> 6;
  int lane = threadIdx.x & 63;
  int es = lane >> 4;   // edge slot 0..3
  int li = lane & 15;   // feature group: 8 features (4 uints)
  int r = blockIdx.x * 4 + wave;
  if (r >= n) return;
  int s = rp[r], e = rp[r + 1];
  float t[8], a[8], b[8];
#pragma unroll
  for (int k = 0; k < 8; ++k) { t[k] = 0.f; a[k] = 0.f; b[k] = 0.f; }
  for (int j = s + es; j < e; j += 4) {
    int c = ci[j];
    float v = cv[j];
    float va = v * sA[c];
    float vb = v * sB[c];
    uint4 u = *(const uint4*)(xb + (size_t)c * 64 + li * 4);
    unsigned int uu[4] = {u.x, u.y, u.z, u.w};
#pragma unroll
    for (int k = 0; k < 4; ++k) {
      float lo = __uint_as_float(uu[k] << 16);
      float hi = __uint_as_float(uu[k] & 0xFFFF0000u);
      t[2 * k]     = fmaf(v, lo, t[2 * k]);
      t[2 * k + 1] = fmaf(v, hi, t[2 * k + 1]);
      a[2 * k]     = fmaf(va, lo, a[2 * k]);
      a[2 * k + 1] = fmaf(va, hi, a[2 * k + 1]);
      b[2 * k]     = fmaf(vb, lo, b[2 * k]);
      b[2 * k + 1] = fmaf(vb, hi, b[2 * k + 1]);
    }
  }
#pragma unroll
  for (int k = 0; k < 8; ++k) {
    t[k] += __shfl_xor(t[k], 16); t[k] += __shfl_xor(t[k], 32);
    a[k] += __shfl_xor(a[k], 16); a[k] += __shfl_xor(a[k], 32);
    b[k] += __shfl_xor(b[k], 16); b[k] += __shfl_xor(b[k], 32);
  }
  if (es == 0) {
    size_t off = (size_t)r * 64 + li * 4;
    uint4 o;
    o.x = pk2(t[0], t[1]); o.y = pk2(t[2], t[3]);
    o.z = pk2(t[4], t[5]); o.w = pk2(t[6], t[7]);
    *(uint4*)(ot + off) = o;
    o.x = pk2(a[0], a[1]); o.y = pk2(a[2], a[3]);
    o.z = pk2(a[4], a[5]); o.w = pk2(a[6], a[7]);
    *(uint4*)(oa + off) = o;
    o.x = pk2(b[0], b[1]); o.y = pk2(b[2], b[3]);
    o.z = pk2(b[4], b[5]); o.w = pk2(b[6], b[7]);
    *(uint4*)(ob + off) = o;
  }
}

// ---------------- fused second hop: 2 sources, 2 outputs, shared indices ----
__global__ __launch_bounds__(256) void sh2_k(
    const int* __restrict__ rp, const int* __restrict__ ci, const float* __restrict__ cv,
    const unsigned int* __restrict__ ga, const unsigned int* __restrict__ gb,
    unsigned int* __restrict__ ya, unsigned int* __restrict__ yb,
    const float* __restrict__ rsa, const float* __restrict__ rsb, int n) {
  int wave = threadIdx.x >> 6;
  int lane = threadIdx.x & 63;
  int es = lane >> 4;
  int li = lane & 15;
  int r = blockIdx.x * 4 + wave;
  if (r >= n) return;
  int s = rp[r], e = rp[r + 1];
  float a[8], b[8];
#pragma unroll
  for (int k = 0; k < 8; ++k) { a[k] = 0.f; b[k] = 0.f; }
  for (int j = s + es; j < e; j += 4) {
    int c = ci[j];
    float v = cv[j];
    size_t off = (size_t)c * 64 + li * 4;
    uint4 u = *(const uint4*)(ga + off);
    uint4 w = *(const uint4*)(gb + off);
    unsigned int uu[4] = {u.x, u.y, u.z, u.w};
    unsigned int ww[4] = {w.x, w.y, w.z, w.w};
#pragma unroll
    for (int k = 0; k < 4; ++k) {
      a[2 * k]     = fmaf(v, __uint_as_float(uu[k] << 16), a[2 * k]);
      a[2 * k + 1] = fmaf(v, __uint_as_float(uu[k] & 0xFFFF0000u), a[2 * k + 1]);
      b[2 * k]     = fmaf(v, __uint_as_float(ww[k] << 16), b[2 * k]);
      b[2 * k + 1] = fmaf(v, __uint_as_float(ww[k] & 0xFFFF0000u), b[2 * k + 1]);
    }
  }
#pragma unroll
  for (int k = 0; k < 8; ++k) {
    a[k] += __shfl_xor(a[k], 16); a[k] += __shfl_xor(a[k], 32);
    b[k] += __shfl_xor(b[k], 16); b[k] += __shfl_xor(b[k], 32);
  }
  if (es == 0) {
    float ra = rsa[r], rb = rsb[r];
    size_t off = (size_t)r * 64 + li * 4;
    uint4 o;
    o.x = pk2(a[0] * ra, a[1] * ra); o.y = pk2(a[2] * ra, a[3] * ra);
    o.z = pk2(a[4] * ra, a[5] * ra); o.w = pk2(a[6] * ra, a[7] * ra);
    *(uint4*)(ya + off) = o;
    o.x = pk2(b[0] * rb, b[1] * rb); o.y = pk2(b[2] * rb, b[3] * rb);
    o.z = pk2(b[4] * rb, b[5] * rb); o.w = pk2(b[6] * rb, b[7] * rb);
    *(uint4*)(yb + off) = o;
  }
}

// ---------------- MFMA fused GEMM: out = 0.5*sum_i Yi@Wi + bias ----------------
// 128 threads, M=32/block; fully unrolled seg*kc so loads pipeline across MFMAs.
struct Y6 { const unsigned short* y[6]; };

__global__ __launch_bounds__(128) void gemm6m_k(
    Y6 ys, const unsigned short* __restrict__ Wt, const float* __restrict__ bias,
    void* __restrict__ outp, int M, const int* flags) {
  int ff = flags[0];
  int wave = threadIdx.x >> 6;
  int lane = threadIdx.x & 63;
  int m = lane & 15, q = lane >> 4;
  int r0 = blockIdx.x * 32 + wave * 16;
  f32x4 acc[8];
#pragma unroll
  for (int nt = 0; nt < 8; ++nt) acc[nt] = (f32x4){0.f, 0.f, 0.f, 0.f};
  int rowA = r0 + m;
  bool okA = rowA < M;
#pragma unroll
  for (int seg = 0; seg < 6; ++seg) {
    const unsigned short* Y = ys.y[seg];
#pragma unroll
    for (int kc = 0; kc < 4; ++kc) {
      bf16x8 af = {0, 0, 0, 0, 0, 0, 0, 0};
      if (okA) af = *(const bf16x8*)(Y + (size_t)rowA * FD + kc * 32 + q * 8);
#pragma unroll
      for (int nt = 0; nt < 8; ++nt) {
        bf16x8 bf = *(const bf16x8*)(Wt + (size_t)(nt * 16 + m) * 768 + seg * 128 + kc * 32 + q * 8);
        acc[nt] = __builtin_amdgcn_mfma_f32_16x16x32_bf16(af, bf, acc[nt], 0, 0, 0);
      }
    }
  }
#pragma unroll
  for (int nt = 0; nt < 8; ++nt) {
    int col = nt * 16 + m;
    float bv = bias[col];
#pragma unroll
    for (int rg = 0; rg < 4; ++rg) {
      int grow = r0 + q * 4 + rg;
      if (grow >= M) continue;
      float v = 0.5f * acc[nt][rg] + bv;
      if (ff) ((float*)outp)[(size_t)grow * FD + col] = v;
      else ((unsigned short*)outp)[(size_t)grow * FD + col] =
          __bfloat16_as_ushort(__float2bfloat16(v));
    }
  }
}

// ---------------- legacy Path B kernels (proven round 4) ----------------
__global__ __launch_bounds__(128) void spmm_k(
    const int* __restrict__ rp, const void* __restrict__ ci, int cif,
    const void* __restrict__ cv, int cvf,
    const void* __restrict__ x, int xf, __hip_bfloat16* __restrict__ y,
    int n, int nnzMax,
    const float* __restrict__ cscale, const float* __restrict__ rscale,
    const int* flags) {
  int ff = flags[0], fi = flags[1];
  int vf = cvf ? 1 : ff;
  int iw = cif ? fi : 0;
  int xw = xf ? ff : 0;
  const int t = threadIdx.x;
  int r0 = blockIdx.x * 4;
  int rend = min(r0 + 4, n);
  for (int r = r0; r < rend; ++r) {
    int s = rp[r], e = rp[r + 1];
    s = max(0, min(s, nnzMax));
    e = max(s, min(e, nnzMax));
    float acc = 0.f;
    for (int j = s; j < e; ++j) {
      int c = ldi(ci, j, iw);
      if ((unsigned)c >= (unsigned)n) c = 0;
      float v = (vf ? ((const float*)cv)[j] : b2f(((const __hip_bfloat16*)cv)[j]));
      if (cscale) v *= cscale[c];
      float xv = xw ? ((const float*)x)[c * FD + t]
                    : b2f(((const __hip_bfloat16*)x)[c * FD + t]);
      acc = fmaf(v, xv, acc);
    }
    if (rscale) acc *= rscale[r];
    y[r * FD + t] = __float2bfloat16(acc);
  }
}

__global__ __launch_bounds__(256) void gemm_k(
    const __hip_bfloat16* __restrict__ Y, const void* __restrict__ W,
    const float* __restrict__ bias, const void* __restrict__ accin,
    void* __restrict__ outp, int M, const int* flags) {
  int ff = flags[0];
  __shared__ __align__(16) float Wl[32 * 128];
  __shared__ __align__(16) float Yl[64 * 36];
  const int t = threadIdx.x;
  const int row0 = blockIdx.x * 64;
  const int c4 = (t & 31) * 4;
  const int r8 = (t >> 5) * 8;
  const int rs = t >> 3;
  const int q = t & 7;
  float acc[8][4];
#pragma unroll
  for (int m = 0; m < 8; ++m)
#pragma unroll
    for (int j = 0; j < 4; ++j) acc[m][j] = 0.f;
  for (int kc = 0; kc < 4; ++kc) {
    if (ff) {
      const float4* Wg4 = (const float4*)((const float*)W + kc * 32 * 128);
#pragma unroll
      for (int i = 0; i < 4; ++i)
        *(float4*)(Wl + (t + i * 256) * 4) = Wg4[t + i * 256];
    } else {
      const ushort4* Wg4 = (const ushort4*)((const unsigned short*)W + kc * 32 * 128);
#pragma unroll
      for (int i = 0; i < 4; ++i) {
        ushort4 u = Wg4[t + i * 256];
        int base = (t + i * 256) * 4;
        Wl[base + 0] = bfu2f(u.x);
        Wl[base + 1] = bfu2f(u.y);
        Wl[base + 2] = bfu2f(u.z);
        Wl[base + 3] = bfu2f(u.w);
      }
    }
#pragma unroll
    for (int i = 0; i < 2; ++i) {
      int rr = rs + i * 32;
      int grow = row0 + rr;
      ushort4 u = make_ushort4(0, 0, 0, 0);
      if (grow < M)
        u = *(const ushort4*)((const unsigned short*)Y + grow * FD + kc * 32 + q * 4);
      float* yd = Yl + rr * 36 + q * 4;
      yd[0] = bfu2f(u.x); yd[1] = bfu2f(u.y); yd[2] = bfu2f(u.z); yd[3] = bfu2f(u.w);
    }
    __syncthreads();
#pragma unroll
    for (int kk = 0; kk < 32; kk += 4) {
      float4 w0 = *(const float4*)(Wl + (kk + 0) * 128 + c4);
      float4 w1 = *(const float4*)(Wl + (kk + 1) * 128 + c4);
      float4 w2 = *(const float4*)(Wl + (kk + 2) * 128 + c4);
      float4 w3 = *(const float4*)(Wl + (kk + 3) * 128 + c4);
#pragma unroll
      for (int m = 0; m < 8; ++m) {
        float4 yv = *(const float4*)(Yl + (r8 + m) * 36 + kk);
        acc[m][0] = fmaf(yv.x, w0.x, acc[m][0]);
        acc[m][1] = fmaf(yv.x, w0.y, acc[m][1]);
        acc[m][2] = fmaf(yv.x, w0.z, acc[m][2]);
        acc[m][3] = fmaf(yv.x, w0.w, acc[m][3]);
        acc[m][0] = fmaf(yv.y, w1.x, acc[m][0]);
        acc[m][1] = fmaf(yv.y, w1.y, acc[m][1]);
        acc[m][2] = fmaf(yv.y, w1.z, acc[m][2]);
        acc[m][3] = fmaf(yv.y, w1.w, acc[m][3]);
        acc[m][0] = fmaf(yv.z, w2.x, acc[m][0]);
        acc[m][1] = fmaf(yv.z, w2.y, acc[m][1]);
        acc[m][2] = fmaf(yv.z, w2.z, acc[m][2]);
        acc[m][3] = fmaf(yv.z, w2.w, acc[m][3]);
        acc[m][0] = fmaf(yv.w, w3.x, acc[m][0]);
        acc[m][1] = fmaf(yv.w, w3.y, acc[m][1]);
        acc[m][2] = fmaf(yv.w, w3.z, acc[m][2]);
        acc[m][3] = fmaf(yv.w, w3.w, acc[m][3]);
      }
    }
    __syncthreads();
  }
  float4 b4 = make_float4(0.f, 0.f, 0.f, 0.f);
  if (bias) b4 = *(const float4*)(bias + c4);
#pragma unroll
  for (int m = 0; m < 8; ++m) {
    int grow = row0 + r8 + m;
    if (grow >= M) continue;
    float4 rv;
    rv.x = 0.5f * acc[m][0] + b4.x;
    rv.y = 0.5f * acc[m][1] + b4.y;
    rv.z = 0.5f * acc[m][2] + b4.z;
    rv.w = 0.5f * acc[m][3] + b4.w;
    if (accin) {
      if (ff) {
        float4 o = *(const float4*)((const float*)accin + grow * FD + c4);
        rv.x += o.x; rv.y += o.y; rv.z += o.z; rv.w += o.w;
      } else {
        ushort4 o = *(const ushort4*)((const unsigned short*)accin + grow * FD + c4);
        rv.x += bfu2f(o.x); rv.y += bfu2f(o.y); rv.z += bfu2f(o.z); rv.w += bfu2f(o.w);
      }
    }
    if (ff) {
      *(float4*)((float*)outp + grow * FD + c4) = rv;
    } else {
      ushort4 so;
      so.x = __bfloat16_as_ushort(__float2bfloat16(rv.x));
      so.y = __bfloat16_as_ushort(__float2bfloat16(rv.y));
      so.z = __bfloat16_as_ushort(__float2bfloat16(rv.z));
      so.w = __bfloat16_as_ushort(__float2bfloat16(rv.w));
      *(ushort4*)((unsigned short*)outp + grow * FD + c4) = so;
    }
  }
}

extern "C" void kernel_launch(void* const* d_in, const int* in_sizes, int n_in,
                              void* d_out, int out_size, void* d_ws, size_t ws_size,
                              hipStream_t stream) {
  const void* x    = d_in[0];
  const void* w_sd = d_in[1];
  const void* b_sd = d_in[2];
  const void* w_ds = d_in[3];
  const void* b_ds = d_in[4];
  const void* w0   = d_in[5];
  const void* b0   = d_in[6];
  const void* w1   = d_in[7];
  const void* b1   = d_in[8];
  const void* w2   = d_in[9];
  const void* b2   = d_in[10];
  const void* w3   = d_in[11];
  const void* b3   = d_in[12];
  const void* a_rows = d_in[13];
  const void* a_cols = d_in[14];
  const void* a_vals = d_in[15];
  const int nnz = in_sizes[13];
  const int N = in_sizes[0] / FD;

  const size_t BUF = ((size_t)N * FD * 2 + 255) & ~(size_t)255;

  auto misc_need = [&](int nbig) -> size_t {
    size_t need = (size_t)nbig * BUF;
    need += ((size_t)10 * N * 4 + 255) & ~(size_t)255;          // degf
    need += 512 + 256 + 1024;                                    // biasf, flags, bsum
    need += (((size_t)(N + 1) * 4 + 255) & ~(size_t)255) * 2;   // rpA, rpT
    need += (((size_t)N * 4 + 255) & ~(size_t)255) * 2;         // curT, cntT
    need += (((size_t)nnz * 4 + 255) & ~(size_t)255) * 5;       // tSrc,tValF,aRow32,aCol32,aValF
    need += (6 * 16384 * 2 + 255) & ~(size_t)255;               // Wt
    return need;
  };
  size_t needA = misc_need(8);
  size_t needB = misc_need(2);

  int pathA = (ws_size >= needA) ? 1 : 0;
  if (!pathA && ws_size < needB) {
    fill_k<<<(out_size + 255) / 256, 256, 0, stream>>>((unsigned short*)d_out, out_size);
    return;
  }

  int nbig = pathA ? 8 : 2;
  char* p = (char*)d_ws;
  char* bufs[8];
  for (int i = 0; i < 8; ++i) bufs[i] = (i < nbig) ? (p + (size_t)i * BUF) : nullptr;
  char* q = p + (size_t)nbig * BUF;
  auto take = [&](size_t bytes) -> char* {
    char* r = q;
    q += (bytes + 255) & ~(size_t)255;
    return r;
  };
  float* degf  = (float*)take((size_t)10 * N * 4);
  float* biasf = (float*)take(512);
  int*   flags = (int*)take(256);
  int*   bsum  = (int*)take(1024);
  int* rpA  = (int*)take((size_t)(N + 1) * 4);
  int* rpT  = (int*)take((size_t)(N + 1) * 4);
  int* curT = (int*)take((size_t)N * 4);
  int* cntT = (int*)take((size_t)N * 4);
  int* tSrc = (int*)take((size_t)nnz * 4);
  float* tValF = (float*)take((size_t)nnz * 4);
  int* aRow32 = (int*)take((size_t)nnz * 4);
  int* aCol32 = (int*)take((size_t)nnz * 4);
  float* aValF = (float*)take((size_t)nnz * 4);
  __hip_bfloat16* Wt = (__hip_bfloat16*)take(6 * 16384 * 2);

  float* u1 = degf;
  float* v1 = degf + N;
  float* e1 = degf + 2 * N;
  float* s1 = degf + 6 * N;
  float* s2 = degf + 7 * N;
  float* s3 = degf + 8 * N;
  float* s4 = degf + 9 * N;

  int eb = (nnz + 255) / 256;
  int nb = (N + 255) / 256;

  detect_k<<<1, 256, 0, stream>>>(x, a_cols, flags);
  cvtall_k<<<eb, 256, 0, stream>>>(a_rows, a_cols, a_vals, nnz, N, aRow32, aCol32, aValF, flags);
  hipMemsetAsync(degf, 0, (size_t)6 * N * 4, stream);
  hipMemsetAsync(cntT, 0, (size_t)N * 4, stream);
  hist_k<<<eb, 256, 0, stream>>>(aRow32, aCol32, aValF, nnz, u1, v1, cntT);
  scanA_k<<<nb, 256, 0, stream>>>(cntT, N, bsum);
  scanB_k<<<1, 256, 0, stream>>>(bsum, nb, rpT + N);
  scanC_k<<<nb, 256, 0, stream>>>(cntT, N, bsum, rpT, curT);
  bsearch_k<<<(N + 256) / 256, 256, 0, stream>>>(aRow32, nnz, N, rpA);
  scatter_k<<<eb, 256, 0, stream>>>(aRow32, aCol32, aValF, nnz, curT, tSrc, tValF);
  deg2_k<<<eb, 256, 0, stream>>>(aRow32, aCol32, aValF, nnz, u1, v1,
                                 e1, degf + 3 * N, degf + 4 * N, degf + 5 * N);
  rsqrt_k<<<(4 * N + 255) / 256, 256, 0, stream>>>(e1, s1, 4 * N);
  bias_k<<<1, FD, 0, stream>>>(b_sd, b_ds, b0, b1, b2, b3, biasf, flags);

  int sg2 = (N + 3) / 4;
  int gg = (N + 63) / 64;
  int gg2 = (N + 31) / 32;

  if (pathA) {
    W6p wargs;
    wargs.w[0] = w_sd; wargs.w[1] = w_ds; wargs.w[2] = w0;
    wargs.w[3] = w1;   wargs.w[4] = w2;   wargs.w[5] = w3;
    wt_k<<<(6 * 16384 + 255) / 256, 256, 0, stream>>>(wargs, Wt, flags);

    __hip_bfloat16* xb = (__hip_bfloat16*)bufs[0];
    cvtx_k<<<(N * FD / 4 + 255) / 256, 256, 0, stream>>>(x, xb, N * FD, flags);

    unsigned int* xbu = (unsigned int*)bufs[0];
    unsigned int* t2 = (unsigned int*)bufs[1];
    unsigned int* g3 = (unsigned int*)bufs[2];
    unsigned int* g6 = (unsigned int*)bufs[3];
    unsigned int* t1 = (unsigned int*)bufs[4];
    unsigned int* g4 = (unsigned int*)bufs[5];
    unsigned int* g5 = (unsigned int*)bufs[6];
    unsigned int* y3 = (unsigned int*)bufs[7];
    unsigned int* y5 = (unsigned int*)bufs[0];  // xb dead after first hops
    unsigned int* y4 = (unsigned int*)bufs[2];  // g3 dead after shA
    unsigned int* y6 = (unsigned int*)bufs[6];  // g5 dead after shA

    fh3_k<<<sg2, 256, 0, stream>>>(rpT, tSrc, tValF, xbu, t2, g3, g6, s1, s3, N);
    fh3_k<<<sg2, 256, 0, stream>>>(rpA, aCol32, aValF, xbu, t1, g4, g5, s2, s4, N);
    sh2_k<<<sg2, 256, 0, stream>>>(rpA, aCol32, aValF, g3, g5, y3, y5, s1, s3, N);
    sh2_k<<<sg2, 256, 0, stream>>>(rpT, tSrc, tValF, g4, g6, y4, y6, s2, s4, N);

    Y6 yargs;
    yargs.y[0] = (const unsigned short*)t1;
    yargs.y[1] = (const unsigned short*)t2;
    yargs.y[2] = (const unsigned short*)y3;
    yargs.y[3] = (const unsigned short*)y4;
    yargs.y[4] = (const unsigned short*)y5;
    yargs.y[5] = (const unsigned short*)y6;
    gemm6m_k<<<gg2, 128, 0, stream>>>(yargs, (const unsigned short*)Wt, biasf, d_out, N, flags);
  } else {
    __hip_bfloat16* Yb = (__hip_bfloat16*)bufs[0];
    __hip_bfloat16* gb = (__hip_bfloat16*)bufs[1];
    spmm_k<<<sg2, 128, 0, stream>>>(rpA, a_cols, 1, a_vals, 0, x, 1, Yb, N, nnz, nullptr, nullptr, flags);
    gemm_k<<<gg, 256, 0, stream>>>(Yb, w_sd, biasf, nullptr, d_out, N, flags);
    spmm_k<<<sg2, 128, 0, stream>>>(rpT, tSrc, 0, tValF, 1, x, 1, Yb, N, nnz, nullptr, nullptr, flags);
    gemm_k<<<gg, 256, 0, stream>>>(Yb, w_ds, nullptr, d_out, d_out, N, flags);
    spmm_k<<<sg2, 128, 0, stream>>>(rpT, tSrc, 0, tValF, 1, x, 1, gb, N, nnz, s1, nullptr, flags);
    spmm_k<<<sg2, 128, 0, stream>>>(rpA, a_cols, 1, a_vals, 0, gb, 0, Yb, N, nnz, nullptr, s1, flags);
    gemm_k<<<gg, 256, 0, stream>>>(Yb, w0, nullptr, d_out, d_out, N, flags);
    spmm_k<<<sg2, 128, 0, stream>>>(rpA, a_cols, 1, a_vals, 0, x, 1, gb, N, nnz, s2, nullptr, flags);
    spmm_k<<<sg2, 128, 0, stream>>>(rpT, tSrc, 0, tValF, 1, gb, 0, Yb, N, nnz, nullptr, s2, flags);
    gemm_k<<<gg, 256, 0, stream>>>(Yb, w1, nullptr, d_out, d_out, N, flags);
    spmm_k<<<sg2, 128, 0, stream>>>(rpA, a_cols, 1, a_vals, 0, x, 1, gb, N, nnz, s4, nullptr, flags);
    spmm_k<<<sg2, 128, 0, stream>>>(rpA, a_cols, 1, a_vals, 0, gb, 0, Yb, N, nnz, nullptr, s3, flags);
    gemm_k<<<gg, 256, 0, stream>>>(Yb, w2, nullptr, d_out, d_out, N, flags);
    spmm_k<<<sg2, 128, 0, stream>>>(rpT, tSrc, 0, tValF, 1, x, 1, gb, N, nnz, s3, nullptr, flags);
    spmm_k<<<sg2, 128, 0, stream>>>(rpT, tSrc, 0, tValF, 1, gb, 0, Yb, N, nnz, nullptr, s4, flags);
    gemm_k<<<gg, 256, 0, stream>>>(Yb, w3, nullptr, d_out, d_out, N, flags);
  }
}